// Round 1
// 5614.640 us; speedup vs baseline: 2.2013x; 2.2013x over previous
//
#include <hip/hip_runtime.h>
#include <hip/hip_bf16.h>
#include <stdint.h>

// Problem dims (fixed): B=16 S=1024 D=768 NH=4 hd=192 DFF=3072 NL=2 C=3
#define Bb 16
#define Ss 1024
#define Dd 768
#define HDd 192

typedef __attribute__((ext_vector_type(8))) short short8;   // 8 bf16 (4 VGPRs)
typedef __attribute__((ext_vector_type(4))) short short4a;  // 4 bf16 (2 VGPRs)
typedef __attribute__((ext_vector_type(4))) float f32x4;

__device__ __forceinline__ short f2bf(float f) {
  union { __hip_bfloat16 h; short s; } u;
  u.h = __float2bfloat16(f);
  return u.s;
}
__device__ __forceinline__ short8 cvt8(float4 lo, float4 hi) {
  short8 r;
  r[0] = f2bf(lo.x); r[1] = f2bf(lo.y); r[2] = f2bf(lo.z); r[3] = f2bf(lo.w);
  r[4] = f2bf(hi.x); r[5] = f2bf(hi.y); r[6] = f2bf(hi.z); r[7] = f2bf(hi.w);
  return r;
}

enum { EPI_F32 = 0, EPI_GELU = 1, EPI_MEANACC = 2 };

// C[m,n] = sum_k A[m,k]*Bw[n,k] (+bias[n], +epilogue). fp32 in/out, bf16 MFMA inside.
// A: [Mchunk,K] row-major fp32 (pointer pre-offset), Bw: [N,K] row-major fp32.
template <int EPI>
__global__ __launch_bounds__(256) void gemm_bt(
    const float* __restrict__ A, const float* __restrict__ Bw,
    const float* __restrict__ bias, void* __restrict__ outp,
    const int N, const int K)
{
  constexpr int TM = 128, TN = 128, BK = 32;
  __shared__ __align__(16) short As[TM * BK];
  __shared__ __align__(16) short Bs[TN * BK];

  const int tid = threadIdx.x;
  const int wave = tid >> 6, lane = tid & 63;
  const int l16 = lane & 15, quad = lane >> 4;
  const int wm = wave >> 1, wn = wave & 1;
  const size_t m0 = (size_t)blockIdx.y * TM;
  const size_t n0 = (size_t)blockIdx.x * TN;

  // staging: 512 chunks of 8 elements per tile; thread handles chunks tid and 256+tid
  const int c0 = tid, c1 = 256 + tid;
  const float* Ag0 = A + (m0 + (c0 >> 2)) * K + (c0 & 3) * 8;
  const float* Ag1 = A + (m0 + (c1 >> 2)) * K + (c1 & 3) * 8;
  const float* Bg0 = Bw + (n0 + (c0 >> 2)) * K + (c0 & 3) * 8;
  const float* Bg1 = Bw + (n0 + (c1 >> 2)) * K + (c1 & 3) * 8;

  f32x4 acc[4][4];
#pragma unroll
  for (int i = 0; i < 4; ++i)
#pragma unroll
    for (int j = 0; j < 4; ++j) acc[i][j] = (f32x4){0.f, 0.f, 0.f, 0.f};

#pragma unroll 1
  for (int k0 = 0; k0 < K; k0 += BK) {
    const short8 a0 = cvt8(*(const float4*)(Ag0 + k0), *(const float4*)(Ag0 + k0 + 4));
    const short8 a1 = cvt8(*(const float4*)(Ag1 + k0), *(const float4*)(Ag1 + k0 + 4));
    const short8 b0 = cvt8(*(const float4*)(Bg0 + k0), *(const float4*)(Bg0 + k0 + 4));
    const short8 b1 = cvt8(*(const float4*)(Bg1 + k0), *(const float4*)(Bg1 + k0 + 4));
    __syncthreads();                 // prev iter's LDS reads done (WAR)
    *(short8*)&As[c0 * 8] = a0;
    *(short8*)&As[c1 * 8] = a1;
    *(short8*)&Bs[c0 * 8] = b0;
    *(short8*)&Bs[c1 * 8] = b1;
    __syncthreads();                 // tiles visible (RAW)

    short8 af[4], bfr[4];
#pragma unroll
    for (int i = 0; i < 4; ++i) {
      af[i]  = *(const short8*)&As[(wm * 64 + i * 16 + l16) * BK + quad * 8];
      bfr[i] = *(const short8*)&Bs[(wn * 64 + i * 16 + l16) * BK + quad * 8];
    }
#pragma unroll
    for (int mt = 0; mt < 4; ++mt)
#pragma unroll
      for (int nt = 0; nt < 4; ++nt)
        acc[mt][nt] = __builtin_amdgcn_mfma_f32_16x16x32_bf16(af[mt], bfr[nt], acc[mt][nt], 0, 0, 0);
  }

  if constexpr (EPI == EPI_MEANACC) {
    // fused mean-over-S: column sums -> atomicAdd into [B,D] fp32 accumulator
    float* eacc = (float*)outp;
    const int b = (int)(m0 >> 10);   // 1024 rows per batch; 128-row tiles never straddle
#pragma unroll
    for (int nt = 0; nt < 4; ++nt) {
      float cs = 0.f;
#pragma unroll
      for (int mt = 0; mt < 4; ++mt)
#pragma unroll
        for (int r = 0; r < 4; ++r) cs += acc[mt][nt][r];
      cs += __shfl_xor(cs, 16, 64);
      cs += __shfl_xor(cs, 32, 64);
      if (quad == 0) {
        const int col = (int)n0 + wn * 64 + nt * 16 + l16;
        atomicAdd(&eacc[b * Dd + col], cs);
      }
    }
  } else {
    float* out = (float*)outp;
#pragma unroll
    for (int nt = 0; nt < 4; ++nt) {
      const size_t col = n0 + wn * 64 + nt * 16 + l16;
      const float bv = bias[col];
#pragma unroll
      for (int mt = 0; mt < 4; ++mt) {
#pragma unroll
        for (int r = 0; r < 4; ++r) {
          const size_t row = m0 + wm * 64 + mt * 16 + quad * 4 + r;
          float v = acc[mt][nt][r] + bv;
          if constexpr (EPI == EPI_GELU)
            v = 0.5f * v * (1.f + erff(v * 0.70710678118654752f));
          out[row * N + col] = v;
        }
      }
    }
  }
}

// ---- MFMA flash attention ----------------------------------------------------
// grid dim3(16,4,8): x = q-tile (64 rows), y = head, z = batch-in-chunk.
// 256 thr = 4 waves; each wave owns 16 q rows.
// Swapped QK^T (S^T = K·Q^T) so per-q softmax stats reduce over quad-lanes only
// (2x shfl_xor) and P is k-register-contiguous for b64 LDS writes.
// K tile [64][192] and V^T tile [192][64] staged fp32->bf16 into XOR-swizzled LDS
// (idx ^= (row&7)<<3 : uniform 16B-slot spread, b128 reads at wave64 floor).
// span_mask is a prefix mask (arange < lengths) => mask via L = idx[b]+1, with
// early break once k0 >= L. T13 defer-rescale skips the O pass when max unchanged.
__global__ __launch_bounds__(256, 2) void flash_attn(
    const float* __restrict__ qkv, const int* __restrict__ idxp,
    float* __restrict__ ctx, const int b0)
{
  __shared__ __align__(16) short Ks[64 * 192];    // 24.0 KB
  __shared__ __align__(16) short Vt[192 * 64];    // 24.0 KB
  __shared__ __align__(16) short Ps[4][16 * 64];  //  8.0 KB (per-wave P)

  const int tid = threadIdx.x, wave = tid >> 6, lane = tid & 63;
  const int l16 = lane & 15, quad = lane >> 4;
  const int qt = blockIdx.x, h = blockIdx.y, bl = blockIdx.z;
  const int b = b0 + bl;
  const int L = idxp[b] + 1;                      // number of valid keys
  const float* base = qkv + (size_t)bl * Ss * (3 * Dd);
  const float* Kb = base + Dd + h * HDd;
  const float* Vb = base + 2 * Dd + h * HDd;

  // Q fragments (MFMA B-operand): row q = qt*64 + wave*16 + l16, hd = c*32+quad*8
  short8 qf[6];
  {
    const float* qp = base + (size_t)(qt * 64 + wave * 16 + l16) * (3 * Dd) + h * HDd;
#pragma unroll
    for (int c = 0; c < 6; ++c)
      qf[c] = cvt8(*(const float4*)(qp + c * 32 + quad * 8),
                   *(const float4*)(qp + c * 32 + quad * 8 + 4));
  }

  f32x4 acc[12];                                  // O accum: 16 q x 192 d per wave
#pragma unroll
  for (int i = 0; i < 12; ++i) acc[i] = (f32x4){0.f, 0.f, 0.f, 0.f};
  float m = -3.0e38f, l = 0.f;
  const float scale = 0.07216878364870322f;       // 1/sqrt(192)

#pragma unroll 1
  for (int kt = 0; kt < 16; ++kt) {
    const int k0 = kt * 64;
    if (k0 >= L) break;                           // prefix mask: rest is masked
    __syncthreads();                              // WAR on Ks/Vt

    // stage K tile [64 k][192 hd] fp32->bf16, swizzled
#pragma unroll
    for (int i = 0; i < 6; ++i) {
      const int c = tid + 256 * i;
      const int kk = c / 24, colc = (c % 24) * 8;
      const float* kp = Kb + (size_t)(k0 + kk) * (3 * Dd) + colc;
      *(short8*)&Ks[(kk * 192 + colc) ^ ((kk & 7) << 3)] =
          cvt8(*(const float4*)kp, *(const float4*)(kp + 4));
    }
    // stage V^T tile [192 d][64 k]: pack (k, k+1) bf16 pairs, swizzled.
    // mapping kp=c&31 keeps LDS writes conflict-free (2-way).
#pragma unroll
    for (int i = 0; i < 6; ++i) {
      const int c = tid + 256 * i;
      const int kp2 = (c & 31) * 2, dc = (c >> 5) * 4;
      const float* vp = Vb + (size_t)(k0 + kp2) * (3 * Dd) + dc;
      const float4 va  = *(const float4*)vp;
      const float4 vb4 = *(const float4*)(vp + 3 * Dd);
#pragma unroll
      for (int j = 0; j < 4; ++j) {
        const int d = dc + j;
        const unsigned int pr =
            (unsigned int)(unsigned short)f2bf(((const float*)&va)[j]) |
            ((unsigned int)(unsigned short)f2bf(((const float*)&vb4)[j]) << 16);
        *(unsigned int*)&Vt[(d * 64 + kp2) ^ ((d & 7) << 3)] = pr;
      }
    }
    __syncthreads();                              // RAW

    // S^T tile [64 k][16 q] = K·Q^T (A = K rows, B = Q rows)
    f32x4 accS[4];
#pragma unroll
    for (int mt = 0; mt < 4; ++mt) accS[mt] = (f32x4){0.f, 0.f, 0.f, 0.f};
#pragma unroll
    for (int c = 0; c < 6; ++c) {
      short8 kf[4];
#pragma unroll
      for (int mt = 0; mt < 4; ++mt) {
        const int row = mt * 16 + l16;
        kf[mt] = *(const short8*)&Ks[(row * 192 + c * 32 + quad * 8) ^ ((l16 & 7) << 3)];
      }
#pragma unroll
      for (int mt = 0; mt < 4; ++mt)
        accS[mt] = __builtin_amdgcn_mfma_f32_16x16x32_bf16(kf[mt], qf[c], accS[mt], 0, 0, 0);
    }

    // lane holds k = k0 + mt*16 + quad*4 + r for q = l16 : scale + padding mask
    float tm = -3.0e38f;
#pragma unroll
    for (int mt = 0; mt < 4; ++mt) {
      const int kg = k0 + mt * 16 + quad * 4;
#pragma unroll
      for (int r = 0; r < 4; ++r) {
        const float sv = (kg + r < L) ? accS[mt][r] * scale : -1.0e30f;
        accS[mt][r] = sv;
        tm = fmaxf(tm, sv);
      }
    }
    tm = fmaxf(tm, __shfl_xor(tm, 16));
    tm = fmaxf(tm, __shfl_xor(tm, 32));
    const float mn = fmaxf(m, tm);
    const bool stay = (mn == m);
    const float sf = __expf(m - mn);
    m = mn;
    l *= sf;

    float rs = 0.f;
#pragma unroll
    for (int mt = 0; mt < 4; ++mt) {
      short4a pw;
#pragma unroll
      for (int r = 0; r < 4; ++r) {
        const float p = __expf(accS[mt][r] - mn);
        rs += p;
        pw[r] = f2bf(p);
      }
      // P[q=l16][k=mt*16+quad*4 .. +3], swizzled; k-contiguous -> one b64 write
      *(short4a*)&Ps[wave][(l16 * 64 + mt * 16 + quad * 4) ^ ((l16 & 7) << 3)] = pw;
    }
    rs += __shfl_xor(rs, 16);
    rs += __shfl_xor(rs, 32);
    l += rs;

    if (!__all(stay)) {                           // defer-rescale (T13)
      f32x4 sv_;
#pragma unroll
      for (int r = 0; r < 4; ++r) sv_[r] = __shfl(sf, quad * 4 + r);
#pragma unroll
      for (int nt = 0; nt < 12; ++nt)
#pragma unroll
        for (int r = 0; r < 4; ++r) acc[nt][r] *= sv_[r];
    }

    // O += P·V : A = P (q rows), B = V^T rows (d)
#pragma unroll
    for (int ks = 0; ks < 2; ++ks) {
      const short8 pa =
          *(const short8*)&Ps[wave][(l16 * 64 + ks * 32 + quad * 8) ^ ((l16 & 7) << 3)];
#pragma unroll
      for (int nt = 0; nt < 12; ++nt) {
        const int d = nt * 16 + l16;
        const short8 vb =
            *(const short8*)&Vt[(d * 64 + ks * 32 + quad * 8) ^ ((d & 7) << 3)];
        acc[nt] = __builtin_amdgcn_mfma_f32_16x16x32_bf16(pa, vb, acc[nt], 0, 0, 0);
      }
    }
  }

  // epilogue: normalize and write ctx[b, q, h*192 + d]
  const float inv = 1.f / l;
  f32x4 iv;
#pragma unroll
  for (int r = 0; r < 4; ++r) iv[r] = __shfl(inv, quad * 4 + r);
  const int qrow = qt * 64 + wave * 16;
#pragma unroll
  for (int r = 0; r < 4; ++r) {
    float* cp = ctx + ((size_t)b * Ss + qrow + quad * 4 + r) * Dd + h * HDd + l16;
#pragma unroll
    for (int nt = 0; nt < 12; ++nt) cp[nt * 16] = acc[nt][r] * iv[r];
  }
}

__global__ __launch_bounds__(256) void calc_idx(const int* __restrict__ mask, int* __restrict__ idx) {
  __shared__ int sm[256];
  const int b = blockIdx.x, tid = threadIdx.x;
  int s = 0;
  for (int i = tid; i < Ss; i += 256) s += mask[b * Ss + i];
  sm[tid] = s;
  __syncthreads();
  for (int o = 128; o > 0; o >>= 1) {
    if (tid < o) sm[tid] += sm[tid + o];
    __syncthreads();
  }
  if (tid == 0) idx[b] = sm[0] - 1;
}

// embedding = accum/1024 + mha_out_b; e1 = emb@asp_w^T+asp_b; e2 = emb@opi_w^T+opi_b (fp32)
// NOTE: eacc may alias e1 (accumulator lives in e1's output slot): all reads of eacc happen
// before the __syncthreads(), all writes after; block b touches only batch b's rows.
__global__ __launch_bounds__(256) void emb_e_kernel(
    const float* __restrict__ eacc, const float* __restrict__ outb,
    const float* __restrict__ aw, const float* __restrict__ ab,
    const float* __restrict__ ow, const float* __restrict__ ob,
    float* __restrict__ e1, float* __restrict__ e2)
{
  __shared__ float emb[Dd];
  const int b = blockIdx.x, tid = threadIdx.x;
  for (int i = tid; i < Dd; i += 256)
    emb[i] = eacc[b * Dd + i] * (1.f / 1024.f) + outb[i];
  __syncthreads();
  for (int n = tid; n < Dd; n += 256) {
    float s1 = ab[n], s2 = ob[n];
    const float* w1 = aw + (size_t)n * Dd;
    const float* w2 = ow + (size_t)n * Dd;
    for (int d = 0; d < Dd; ++d) {
      const float ev = emb[d];
      s1 += ev * w1[d];
      s2 += ev * w2[d];
    }
    e1[b * Dd + n] = s1;
    e2[b * Dd + n] = s2;
  }
}

__global__ __launch_bounds__(64) void imp_kernel(
    const float* __restrict__ e1, const float* __restrict__ e2,
    const float* __restrict__ wa, const float* __restrict__ ba,
    const float* __restrict__ wo, const float* __restrict__ bo,
    float* __restrict__ outa, float* __restrict__ outo)
{
  const int id = blockIdx.x, lane = threadIdx.x;
  const int b = id >> 2, which = (id >> 1) & 1, c = id & 1;
  const float* e = which ? e2 : e1;
  const float* w = which ? wo : wa;
  const float* bb = which ? bo : ba;
  float s = 0.f;
  for (int d = lane; d < Dd; d += 64) s += e[b * Dd + d] * w[c * Dd + d];
  for (int off = 32; off > 0; off >>= 1) s += __shfl_xor(s, off, 64);
  if (lane == 0) {
    float* o = which ? outo : outa;
    o[b * 2 + c] = s + bb[c];
  }
}

// se1: row0<-e1 then row idx<-e2 ; se2: row idx<-e2 then row0<-e1
__global__ __launch_bounds__(256) void scatter_kernel(
    const float* __restrict__ x, const float* __restrict__ e1,
    const float* __restrict__ e2, const int* __restrict__ idx,
    float* __restrict__ h1, float* __restrict__ h2)
{
  const int row = blockIdx.x;
  const int b = row >> 10, s = row & 1023;
  const int ix = idx[b];
  const size_t base = (size_t)row * Dd;
  for (int i = threadIdx.x; i < Dd; i += 256) {
    const float xv = x[base + i];
    const float v1 = e1[b * Dd + i];
    const float v2 = e2[b * Dd + i];
    h1[base + i] = (s == ix) ? v2 : ((s == 0) ? v1 : xv);
    h2[base + i] = (s == 0) ? v1 : ((s == ix) ? v2 : xv);
  }
}

// h = LayerNorm(pre + h)*g + b  (in place on h), one wave per row; pre/h pre-offset per chunk
__global__ __launch_bounds__(64) void ln_kernel(
    const float* __restrict__ pre, float* __restrict__ h,
    const float* __restrict__ g, const float* __restrict__ bb)
{
  const int row = blockIdx.x, lane = threadIdx.x;
  const size_t base = (size_t)row * Dd;
  float v[12];
  float s = 0.f, sq = 0.f;
#pragma unroll
  for (int t = 0; t < 12; ++t) {
    const int i = t * 64 + lane;
    const float val = pre[base + i] + h[base + i];
    v[t] = val;
    s += val;
    sq += val * val;
  }
#pragma unroll
  for (int off = 32; off > 0; off >>= 1) {
    s += __shfl_xor(s, off, 64);
    sq += __shfl_xor(sq, off, 64);
  }
  const float m = s * (1.f / 768.f);
  float var = sq * (1.f / 768.f) - m * m;
  var = fmaxf(var, 0.f);
  const float r = rsqrtf(var + 1e-12f);
#pragma unroll
  for (int t = 0; t < 12; ++t) {
    const int i = t * 64 + lane;
    h[base + i] = (v[t] - m) * r * g[i] + bb[i];
  }
}

// logits[row,0..2] = h[row,:]@w[c,:] + b[c]; blocks 0..16383 -> asp(h1), rest -> opi(h2)
__global__ __launch_bounds__(64) void logits_kernel(
    const float* __restrict__ h1, const float* __restrict__ h2,
    const float* __restrict__ wa, const float* __restrict__ ba,
    const float* __restrict__ wo, const float* __restrict__ bo,
    float* __restrict__ outa, float* __restrict__ outo)
{
  const int id = blockIdx.x, lane = threadIdx.x;
  const int which = id >> 14;
  const int row = id & 16383;
  const float* h = which ? h2 : h1;
  const float* w = which ? wo : wa;
  const float* bc = which ? bo : ba;
  const size_t base = (size_t)row * Dd;
  float s0 = 0.f, s1 = 0.f, s2 = 0.f;
#pragma unroll
  for (int t = 0; t < 12; ++t) {
    const int i = t * 64 + lane;
    const float hv = h[base + i];
    s0 += hv * w[i];
    s1 += hv * w[Dd + i];
    s2 += hv * w[2 * Dd + i];
  }
#pragma unroll
  for (int off = 32; off > 0; off >>= 1) {
    s0 += __shfl_xor(s0, off, 64);
    s1 += __shfl_xor(s1, off, 64);
    s2 += __shfl_xor(s2, off, 64);
  }
  if (lane == 0) {
    float* o = which ? outo : outa;
    o[(size_t)row * 3 + 0] = s0 + bc[0];
    o[(size_t)row * 3 + 1] = s1 + bc[1];
    o[(size_t)row * 3 + 2] = s2 + bc[2];
  }
}

__global__ __launch_bounds__(256) void copy16(const uint4* __restrict__ s, uint4* __restrict__ d, int n) {
  const int i = blockIdx.x * 256 + threadIdx.x;
  if (i < n) d[i] = s[i];
}

extern "C" void kernel_launch(void* const* d_in, const int* in_sizes, int n_in,
                              void* d_out, int out_size, void* d_ws, size_t ws_size,
                              hipStream_t stream)
{
  (void)in_sizes; (void)n_in; (void)out_size; (void)d_ws; (void)ws_size;  // d_ws UNUSED: size unknown, see R3 post-mortem
  const float* x        = (const float*)d_in[0];
  const int*   mask     = (const int*)d_in[1];
  const float* mha_in_w = (const float*)d_in[2];
  const float* mha_in_b = (const float*)d_in[3];
  const float* mha_out_w= (const float*)d_in[4];
  const float* mha_out_b= (const float*)d_in[5];
  const float* asp_w    = (const float*)d_in[6];
  const float* asp_b    = (const float*)d_in[7];
  const float* opi_w    = (const float*)d_in[8];
  const float* opi_b    = (const float*)d_in[9];
  const float* ia_w     = (const float*)d_in[10];
  const float* ia_b     = (const float*)d_in[11];
  const float* io_w     = (const float*)d_in[12];
  const float* io_b     = (const float*)d_in[13];
  const float* cls_a_w  = (const float*)d_in[26];
  const float* cls_a_b  = (const float*)d_in[27];
  const float* cls_o_w  = (const float*)d_in[28];
  const float* cls_o_b  = (const float*)d_in[29];

  // ---- output layout (fp32 elements, return order). ALL scratch lives in dead d_out regions. ----
  float* out   = (float*)d_out;
  float* o_la  = out;                        // logits_asp [16,1024,3]
  float* o_lo  = out + 49152;                // logits_opi; first 64B double as idx[16] until phase 9
  float* o_x   = out + 98304;                // x copy (written LAST); scratch: ctx -> interbuf+preC
  float* o_se1 = o_x + 12582912;             // se1; scratch: qkv chunk buffer until scatter
  float* o_se2 = o_se1 + 12582912;           // se2
  float* o_ia  = o_se2 + 12582912;           // imp_asp [16,2]
  float* o_io  = o_ia + 32;
  float* o_e1  = o_io + 32;                  // e1 [16,768]; doubles as mean accumulator before emb_e
  float* o_e2  = o_e1 + 12288;

  float* ctx      = o_x;                     // [16384,768] attention phases
  float* interbuf = o_x;                     // [2048,3072] FFN phases (ctx dead)
  float* preC     = o_x + 6291456;           // [2048,768] per-chunk pre-LN
  float* qkvbuf   = o_se1;                   // [8192,2304] fp32 = 75.5MB, spans o_se1 into
                                             // o_se2; both dead until scatter
  float* h1       = o_se1;
  float* h2       = o_se2;
  float* eacc     = o_e1;                    // [16,768] accumulator (aliases e1 slot; safe, see emb_e)
  int*   idxp     = (int*)o_lo;              // [16] until logits overwrites

  hipMemsetAsync(eacc, 0, Bb * Dd * sizeof(float), stream);
  calc_idx<<<Bb, 256, 0, stream>>>(mask, idxp);

  // QKV + MFMA flash attention, 2 chunks of 8 batches ([8192,2304] fp32 in qkvbuf)
  for (int c = 0; c < 2; ++c) {
    gemm_bt<EPI_F32><<<dim3(2304 / 128, 8192 / 128), 256, 0, stream>>>(
        x + (size_t)c * 8192 * Dd, mha_in_w, mha_in_b, qkvbuf, 2304, 768);
    flash_attn<<<dim3(16, 4, 8), 256, 0, stream>>>(qkvbuf, idxp, ctx, c * 8);
  }

  // out-proj with fused mean-over-S -> eacc (full M)
  gemm_bt<EPI_MEANACC><<<dim3(768 / 128, 16384 / 128), 256, 0, stream>>>(
      ctx, mha_out_w, nullptr, eacc, 768, 768);

  emb_e_kernel<<<Bb, 256, 0, stream>>>(eacc, mha_out_b, asp_w, asp_b, opi_w, opi_b,
                                       o_e1, o_e2);
  imp_kernel<<<64, 64, 0, stream>>>(o_e1, o_e2, ia_w, ia_b, io_w, io_b, o_ia, o_io);
  scatter_kernel<<<16384, 256, 0, stream>>>(x, o_e1, o_e2, idxp, h1, h2);

  // decoder stacks in place on h1/h2; inter [2048,3072] + preC [2048,768] in o_x; LN per chunk
  for (int st = 0; st < 2; ++st) {
    float* h = st ? h2 : h1;
    const float* Wi = (const float*)d_in[14 + st * 6];
    const float* bi = (const float*)d_in[15 + st * 6];
    const float* Wo = (const float*)d_in[16 + st * 6];
    const float* bo = (const float*)d_in[17 + st * 6];
    const float* lg = (const float*)d_in[18 + st * 6];
    const float* lb = (const float*)d_in[19 + st * 6];
    for (int l = 0; l < 2; ++l) {
      for (int c = 0; c < 8; ++c) {
        float* hc = h + (size_t)c * 2048 * Dd;
        gemm_bt<EPI_GELU><<<dim3(3072 / 128, 2048 / 128), 256, 0, stream>>>(
            hc, Wi + (size_t)l * 3072 * 768, bi + l * 3072, interbuf, 3072, 768);
        gemm_bt<EPI_F32><<<dim3(768 / 128, 2048 / 128), 256, 0, stream>>>(
            interbuf, Wo + (size_t)l * 768 * 3072, bo + l * 768, preC, 768, 3072);
        ln_kernel<<<2048, 64, 0, stream>>>(preC, hc, lg + l * 768, lb + l * 768);
      }
    }
  }

  logits_kernel<<<32768, 64, 0, stream>>>(h1, h2, cls_a_w, cls_a_b, cls_o_w, cls_o_b,
                                          o_la, o_lo);
  // x copy LAST (o_x served as ctx/interbuf/preC scratch until here)
  copy16<<<12288, 256, 0, stream>>>((const uint4*)x, (uint4*)o_x, 3145728);
}

// Round 2
// 3947.689 us; speedup vs baseline: 3.1308x; 1.4223x over previous
//
#include <hip/hip_runtime.h>
#include <hip/hip_bf16.h>
#include <stdint.h>

// Problem dims (fixed): B=16 S=1024 D=768 NH=4 hd=192 DFF=3072 NL=2 C=3
#define Bb 16
#define Ss 1024
#define Dd 768
#define HDd 192

typedef __attribute__((ext_vector_type(8))) short short8;   // 8 bf16 (4 VGPRs)
typedef __attribute__((ext_vector_type(4))) short short4a;  // 4 bf16 (2 VGPRs)
typedef __attribute__((ext_vector_type(4))) float f32x4;

__device__ __forceinline__ short f2bf(float f) {
  union { __hip_bfloat16 h; short s; } u;
  u.h = __float2bfloat16(f);
  return u.s;
}
__device__ __forceinline__ short8 cvt8(float4 lo, float4 hi) {
  short8 r;
  r[0] = f2bf(lo.x); r[1] = f2bf(lo.y); r[2] = f2bf(lo.z); r[3] = f2bf(lo.w);
  r[4] = f2bf(hi.x); r[5] = f2bf(hi.y); r[6] = f2bf(hi.z); r[7] = f2bf(hi.w);
  return r;
}
// async global->LDS 16B (m97 staging). LDS dest is wave-uniform base + lane*16:
// per-lane dest pointers must be lane-contiguous within each wave.
__device__ __forceinline__ void gload_lds16(const void* g, void* l) {
  __builtin_amdgcn_global_load_lds(
      (const __attribute__((address_space(1))) void*)g,
      (__attribute__((address_space(3))) void*)l, 16, 0, 0);
}

enum { EPI_F32 = 0, EPI_GELU = 1, EPI_MEANACC = 2 };

// C[m,n] = sum_k A[m,k]*Bw[n,k] (+bias[n], +epilogue). bf16 operands in global,
// m97 structure: global_load_lds width-16 staging, 128x128 tile, BK=32.
// Linear LDS [128][32] (64B rows) is conflict-free for ds_read_b128 at this BK.
// OBF=1 -> store bf16 (consumer is another gemm), else fp32.
template <int EPI, int OBF>
__global__ __launch_bounds__(256) void gemm_bf(
    const short* __restrict__ A, const short* __restrict__ Bw,
    const float* __restrict__ bias, void* __restrict__ outp,
    const int N, const int K)
{
  constexpr int TM = 128, TN = 128, BK = 32;
  __shared__ __align__(16) short As[TM * BK];   // 8 KB
  __shared__ __align__(16) short Bs[TN * BK];   // 8 KB

  const int tid = threadIdx.x;
  const int wave = tid >> 6, lane = tid & 63;
  const int l16 = lane & 15, quad = lane >> 4;
  const int wm = wave >> 1, wn = wave & 1;
  const size_t m0 = (size_t)blockIdx.y * TM;
  const size_t n0 = (size_t)blockIdx.x * TN;

  // 512 16B-chunks per tile: chunk c = (row=c>>2, u=c&3); thread stages c and c+256
  const int c0 = tid, c1 = tid + 256;
  const short* Ag0 = A + (m0 + (c0 >> 2)) * K + (c0 & 3) * 8;
  const short* Ag1 = A + (m0 + (c1 >> 2)) * K + (c1 & 3) * 8;
  const short* Bg0 = Bw + (n0 + (c0 >> 2)) * K + (c0 & 3) * 8;
  const short* Bg1 = Bw + (n0 + (c1 >> 2)) * K + (c1 & 3) * 8;
  short* As0 = &As[c0 * 8];
  short* As1 = &As[c1 * 8];
  short* Bs0 = &Bs[c0 * 8];
  short* Bs1 = &Bs[c1 * 8];

  f32x4 acc[4][4];
#pragma unroll
  for (int i = 0; i < 4; ++i)
#pragma unroll
    for (int j = 0; j < 4; ++j) acc[i][j] = (f32x4){0.f, 0.f, 0.f, 0.f};

#pragma unroll 1
  for (int k0 = 0; k0 < K; k0 += BK) {
    __syncthreads();                 // WAR: prev iter's LDS reads done
    gload_lds16(Ag0 + k0, As0);
    gload_lds16(Ag1 + k0, As1);
    gload_lds16(Bg0 + k0, Bs0);
    gload_lds16(Bg1 + k0, Bs1);
    __syncthreads();                 // RAW: vmcnt drained before barrier

    short8 af[4], bfr[4];
#pragma unroll
    for (int i = 0; i < 4; ++i) {
      af[i]  = *(const short8*)&As[(wm * 64 + i * 16 + l16) * BK + quad * 8];
      bfr[i] = *(const short8*)&Bs[(wn * 64 + i * 16 + l16) * BK + quad * 8];
    }
#pragma unroll
    for (int mt = 0; mt < 4; ++mt)
#pragma unroll
      for (int nt = 0; nt < 4; ++nt)
        acc[mt][nt] = __builtin_amdgcn_mfma_f32_16x16x32_bf16(af[mt], bfr[nt], acc[mt][nt], 0, 0, 0);
  }

  if constexpr (EPI == EPI_MEANACC) {
    // fused mean-over-S: column sums -> atomicAdd into [B,D] fp32 accumulator
    float* eacc = (float*)outp;
    const int b = (int)(m0 >> 10);   // 1024 rows per batch; 128-row tiles never straddle
#pragma unroll
    for (int nt = 0; nt < 4; ++nt) {
      float cs = 0.f;
#pragma unroll
      for (int mt = 0; mt < 4; ++mt)
#pragma unroll
        for (int r = 0; r < 4; ++r) cs += acc[mt][nt][r];
      cs += __shfl_xor(cs, 16, 64);
      cs += __shfl_xor(cs, 32, 64);
      if (quad == 0) {
        const int col = (int)n0 + wn * 64 + nt * 16 + l16;
        atomicAdd(&eacc[b * Dd + col], cs);
      }
    }
  } else {
#pragma unroll
    for (int nt = 0; nt < 4; ++nt) {
      const size_t col = n0 + wn * 64 + nt * 16 + l16;
      const float bv = bias[col];
#pragma unroll
      for (int mt = 0; mt < 4; ++mt) {
#pragma unroll
        for (int r = 0; r < 4; ++r) {
          const size_t row = m0 + wm * 64 + mt * 16 + quad * 4 + r;
          float v = acc[mt][nt][r] + bv;
          if constexpr (EPI == EPI_GELU)
            v = 0.5f * v * (1.f + erff(v * 0.70710678118654752f));
          if constexpr (OBF)
            ((short*)outp)[row * N + col] = f2bf(v);
          else
            ((float*)outp)[row * N + col] = v;
        }
      }
    }
  }
}

// ---- MFMA flash attention on bf16 qkv ---------------------------------------
// grid dim3(16,4,16): x = q-tile (64 rows), y = head, z = batch. 4 waves/block,
// each wave owns 16 q rows. Swapped QK^T; K tile staged via global_load_lds with
// source-side swizzle (linear dest + inverse-swizzled source + swizzled read);
// V^T via register transpose. ctx written bf16 (consumer is meanacc gemm).
__global__ __launch_bounds__(256, 2) void flash_attn(
    const short* __restrict__ qkv, const int* __restrict__ idxp,
    short* __restrict__ ctx)
{
  __shared__ __align__(16) short Ks[64 * 192];    // 24.0 KB
  __shared__ __align__(16) short Vt[192 * 64];    // 24.0 KB
  __shared__ __align__(16) short Ps[4][16 * 64];  //  8.0 KB (per-wave P)

  const int tid = threadIdx.x, wave = tid >> 6, lane = tid & 63;
  const int l16 = lane & 15, quad = lane >> 4;
  const int qt = blockIdx.x, h = blockIdx.y, b = blockIdx.z;
  const int L = idxp[b] + 1;                      // number of valid keys
  const short* base = qkv + (size_t)b * Ss * (3 * Dd);
  const short* Kb = base + Dd + h * HDd;
  const short* Vb = base + 2 * Dd + h * HDd;

  // Q fragments (MFMA B-operand): direct bf16 loads
  short8 qf[6];
  {
    const short* qp = base + (size_t)(qt * 64 + wave * 16 + l16) * (3 * Dd) + h * HDd;
#pragma unroll
    for (int c = 0; c < 6; ++c) qf[c] = *(const short8*)(qp + c * 32 + quad * 8);
  }

  f32x4 acc[12];                                  // O accum: 16 q x 192 d per wave
#pragma unroll
  for (int i = 0; i < 12; ++i) acc[i] = (f32x4){0.f, 0.f, 0.f, 0.f};
  float m = -3.0e38f, l = 0.f;
  const float scale = 0.07216878364870322f;       // 1/sqrt(192)

#pragma unroll 1
  for (int kt = 0; kt < 16; ++kt) {
    const int k0 = kt * 64;
    if (k0 >= L) break;                           // prefix mask: rest is masked
    __syncthreads();                              // WAR on Ks/Vt

    // stage K tile [64 k][192 hd] via gload_lds; physical 16B-unit (kk,u) holds
    // global unit u^(kk&7) so the swizzled read below lands on logical data
#pragma unroll
    for (int i = 0; i < 6; ++i) {
      const int c = tid + 256 * i;
      const int kk = c / 24, u = c % 24;
      gload_lds16(Kb + (size_t)(k0 + kk) * (3 * Dd) + (u ^ (kk & 7)) * 8, &Ks[c * 8]);
    }
    // stage V^T tile [192 d][64 k]: pack (k,k+1) bf16 pairs, swizzled
#pragma unroll
    for (int i = 0; i < 6; ++i) {
      const int c = tid + 256 * i;
      const int kp2 = (c & 31) * 2, dc = (c >> 5) * 4;
      const short* vp = Vb + (size_t)(k0 + kp2) * (3 * Dd) + dc;
      const short4a va  = *(const short4a*)vp;
      const short4a vb4 = *(const short4a*)(vp + 3 * Dd);
#pragma unroll
      for (int j = 0; j < 4; ++j) {
        const int d = dc + j;
        const unsigned int pr = (unsigned int)(unsigned short)va[j] |
                                ((unsigned int)(unsigned short)vb4[j] << 16);
        *(unsigned int*)&Vt[(d * 64 + kp2) ^ ((d & 7) << 3)] = pr;
      }
    }
    __syncthreads();                              // RAW (vmcnt+lgkm drained)

    // S^T tile [64 k][16 q] = K·Q^T
    f32x4 accS[4];
#pragma unroll
    for (int mt = 0; mt < 4; ++mt) accS[mt] = (f32x4){0.f, 0.f, 0.f, 0.f};
#pragma unroll
    for (int c = 0; c < 6; ++c) {
      short8 kf[4];
#pragma unroll
      for (int mt = 0; mt < 4; ++mt) {
        const int row = mt * 16 + l16;
        kf[mt] = *(const short8*)&Ks[(row * 192 + c * 32 + quad * 8) ^ ((l16 & 7) << 3)];
      }
#pragma unroll
      for (int mt = 0; mt < 4; ++mt)
        accS[mt] = __builtin_amdgcn_mfma_f32_16x16x32_bf16(kf[mt], qf[c], accS[mt], 0, 0, 0);
    }

    // lane holds k = k0 + mt*16 + quad*4 + r for q = l16 : scale + padding mask
    float tm = -3.0e38f;
#pragma unroll
    for (int mt = 0; mt < 4; ++mt) {
      const int kg = k0 + mt * 16 + quad * 4;
#pragma unroll
      for (int r = 0; r < 4; ++r) {
        const float sv = (kg + r < L) ? accS[mt][r] * scale : -1.0e30f;
        accS[mt][r] = sv;
        tm = fmaxf(tm, sv);
      }
    }
    tm = fmaxf(tm, __shfl_xor(tm, 16));
    tm = fmaxf(tm, __shfl_xor(tm, 32));
    const float mn = fmaxf(m, tm);
    const bool stay = (mn == m);
    const float sf = __expf(m - mn);
    m = mn;
    l *= sf;

    float rs = 0.f;
#pragma unroll
    for (int mt = 0; mt < 4; ++mt) {
      short4a pw;
#pragma unroll
      for (int r = 0; r < 4; ++r) {
        const float p = __expf(accS[mt][r] - mn);
        rs += p;
        pw[r] = f2bf(p);
      }
      *(short4a*)&Ps[wave][(l16 * 64 + mt * 16 + quad * 4) ^ ((l16 & 7) << 3)] = pw;
    }
    rs += __shfl_xor(rs, 16);
    rs += __shfl_xor(rs, 32);
    l += rs;

    if (!__all(stay)) {                           // defer-rescale (T13)
      f32x4 sv_;
#pragma unroll
      for (int r = 0; r < 4; ++r) sv_[r] = __shfl(sf, quad * 4 + r);
#pragma unroll
      for (int nt = 0; nt < 12; ++nt)
#pragma unroll
        for (int r = 0; r < 4; ++r) acc[nt][r] *= sv_[r];
    }

    // O += P·V
#pragma unroll
    for (int ks = 0; ks < 2; ++ks) {
      const short8 pa =
          *(const short8*)&Ps[wave][(l16 * 64 + ks * 32 + quad * 8) ^ ((l16 & 7) << 3)];
#pragma unroll
      for (int nt = 0; nt < 12; ++nt) {
        const int d = nt * 16 + l16;
        const short8 vb =
            *(const short8*)&Vt[(d * 64 + ks * 32 + quad * 8) ^ ((d & 7) << 3)];
        acc[nt] = __builtin_amdgcn_mfma_f32_16x16x32_bf16(pa, vb, acc[nt], 0, 0, 0);
      }
    }
  }

  // epilogue: normalize and write ctx[b, q, h*192 + d] as bf16
  const float inv = 1.f / l;
  f32x4 iv;
#pragma unroll
  for (int r = 0; r < 4; ++r) iv[r] = __shfl(inv, quad * 4 + r);
  const int qrow = qt * 64 + wave * 16;
#pragma unroll
  for (int r = 0; r < 4; ++r) {
    short* cp = ctx + ((size_t)b * Ss + qrow + quad * 4 + r) * Dd + h * HDd + l16;
#pragma unroll
    for (int nt = 0; nt < 12; ++nt) cp[nt * 16] = f2bf(acc[nt][r] * iv[r]);
  }
}

__global__ __launch_bounds__(256) void calc_idx(const int* __restrict__ mask, int* __restrict__ idx) {
  __shared__ int sm[256];
  const int b = blockIdx.x, tid = threadIdx.x;
  int s = 0;
  for (int i = tid; i < Ss; i += 256) s += mask[b * Ss + i];
  sm[tid] = s;
  __syncthreads();
  for (int o = 128; o > 0; o >>= 1) {
    if (tid < o) sm[tid] += sm[tid + o];
    __syncthreads();
  }
  if (tid == 0) idx[b] = sm[0] - 1;
}

// fp32 -> bf16, 8 elems/thread
__global__ __launch_bounds__(256) void cvt_bf(const float* __restrict__ s,
                                              short* __restrict__ d, int n8) {
  const int i = blockIdx.x * 256 + threadIdx.x;
  if (i < n8)
    *(short8*)(d + (size_t)i * 8) = cvt8(((const float4*)s)[i * 2],
                                         ((const float4*)s)[i * 2 + 1]);
}

// e1/e2: one thread per (which,n,b). 16-lane groups share a w-row (broadcast loads).
// emb[b][d] = eacc[b][d]/1024 + outb[d] recomputed in-flight (trivial FLOPs).
__global__ __launch_bounds__(256) void e12_kernel(
    const float* __restrict__ eacc, const float* __restrict__ outb,
    const float* __restrict__ aw, const float* __restrict__ ab,
    const float* __restrict__ ow, const float* __restrict__ ob,
    float* __restrict__ e1, float* __restrict__ e2)
{
  const int id = blockIdx.x * 256 + threadIdx.x;  // 0..24575
  const int which = (id >= 12288);
  const int r = which ? id - 12288 : id;
  const int n = r >> 4, b = r & 15;
  const float* w = (which ? ow : aw) + (size_t)n * Dd;
  const float* ea = eacc + b * Dd;
  float s = 0.f;
#pragma unroll 4
  for (int d = 0; d < Dd; d += 4) {
    const float4 wv = *(const float4*)(w + d);
    const float4 ev = *(const float4*)(ea + d);
    const float4 bv = *(const float4*)(outb + d);
    s += (ev.x * (1.f / 1024.f) + bv.x) * wv.x + (ev.y * (1.f / 1024.f) + bv.y) * wv.y
       + (ev.z * (1.f / 1024.f) + bv.z) * wv.z + (ev.w * (1.f / 1024.f) + bv.w) * wv.w;
  }
  s += which ? ob[n] : ab[n];
  (which ? e2 : e1)[b * Dd + n] = s;
}

__global__ __launch_bounds__(64) void imp_kernel(
    const float* __restrict__ e1, const float* __restrict__ e2,
    const float* __restrict__ wa, const float* __restrict__ ba,
    const float* __restrict__ wo, const float* __restrict__ bo,
    float* __restrict__ outa, float* __restrict__ outo)
{
  const int id = blockIdx.x, lane = threadIdx.x;
  const int b = id >> 2, which = (id >> 1) & 1, c = id & 1;
  const float* e = which ? e2 : e1;
  const float* w = which ? wo : wa;
  const float* bb = which ? bo : ba;
  float s = 0.f;
  for (int d = lane; d < Dd; d += 64) s += e[b * Dd + d] * w[c * Dd + d];
  for (int off = 32; off > 0; off >>= 1) s += __shfl_xor(s, off, 64);
  if (lane == 0) {
    float* o = which ? outo : outa;
    o[b * 2 + c] = s + bb[c];
  }
}

// se1: row0<-e1 then row idx<-e2 ; se2: row idx<-e2 then row0<-e1
__global__ __launch_bounds__(256) void scatter_kernel(
    const float* __restrict__ x, const float* __restrict__ e1,
    const float* __restrict__ e2, const int* __restrict__ idx,
    float* __restrict__ h1, float* __restrict__ h2)
{
  const int row = blockIdx.x;
  const int b = row >> 10, s = row & 1023;
  const int ix = idx[b];
  const size_t base = (size_t)row * Dd;
  for (int i = threadIdx.x; i < Dd; i += 256) {
    const float xv = x[base + i];
    const float v1 = e1[b * Dd + i];
    const float v2 = e2[b * Dd + i];
    h1[base + i] = (s == ix) ? v2 : ((s == 0) ? v1 : xv);
    h2[base + i] = (s == 0) ? v1 : ((s == ix) ? v2 : xv);
  }
}

// h = LayerNorm(pre + h)*g + b (in place on h) + bf16 shadow hb for the next gemm
__global__ __launch_bounds__(64) void ln_kernel(
    const float* __restrict__ pre, float* __restrict__ h, short* __restrict__ hb,
    const float* __restrict__ g, const float* __restrict__ bb)
{
  const int row = blockIdx.x, lane = threadIdx.x;
  const size_t base = (size_t)row * Dd;
  float v[12];
  float s = 0.f, sq = 0.f;
#pragma unroll
  for (int t = 0; t < 12; ++t) {
    const int i = t * 64 + lane;
    const float val = pre[base + i] + h[base + i];
    v[t] = val;
    s += val;
    sq += val * val;
  }
#pragma unroll
  for (int off = 32; off > 0; off >>= 1) {
    s += __shfl_xor(s, off, 64);
    sq += __shfl_xor(sq, off, 64);
  }
  const float m = s * (1.f / 768.f);
  float var = sq * (1.f / 768.f) - m * m;
  var = fmaxf(var, 0.f);
  const float r = rsqrtf(var + 1e-12f);
#pragma unroll
  for (int t = 0; t < 12; ++t) {
    const int i = t * 64 + lane;
    const float o = (v[t] - m) * r * g[i] + bb[i];
    h[base + i] = o;
    hb[base + i] = f2bf(o);
  }
}

// logits[row,0..2] = h[row,:]@w[c,:] + b[c]; blocks 0..16383 -> asp(h1), rest -> opi(h2)
__global__ __launch_bounds__(64) void logits_kernel(
    const float* __restrict__ h1, const float* __restrict__ h2,
    const float* __restrict__ wa, const float* __restrict__ ba,
    const float* __restrict__ wo, const float* __restrict__ bo,
    float* __restrict__ outa, float* __restrict__ outo)
{
  const int id = blockIdx.x, lane = threadIdx.x;
  const int which = id >> 14;
  const int row = id & 16383;
  const float* h = which ? h2 : h1;
  const float* w = which ? wo : wa;
  const float* bc = which ? bo : ba;
  const size_t base = (size_t)row * Dd;
  float s0 = 0.f, s1 = 0.f, s2 = 0.f;
#pragma unroll
  for (int t = 0; t < 12; ++t) {
    const int i = t * 64 + lane;
    const float hv = h[base + i];
    s0 += hv * w[i];
    s1 += hv * w[Dd + i];
    s2 += hv * w[2 * Dd + i];
  }
#pragma unroll
  for (int off = 32; off > 0; off >>= 1) {
    s0 += __shfl_xor(s0, off, 64);
    s1 += __shfl_xor(s1, off, 64);
    s2 += __shfl_xor(s2, off, 64);
  }
  if (lane == 0) {
    float* o = which ? outo : outa;
    o[(size_t)row * 3 + 0] = s0 + bc[0];
    o[(size_t)row * 3 + 1] = s1 + bc[1];
    o[(size_t)row * 3 + 2] = s2 + bc[2];
  }
}

__global__ __launch_bounds__(256) void copy16(const uint4* __restrict__ s, uint4* __restrict__ d, int n) {
  const int i = blockIdx.x * 256 + threadIdx.x;
  if (i < n) d[i] = s[i];
}

extern "C" void kernel_launch(void* const* d_in, const int* in_sizes, int n_in,
                              void* d_out, int out_size, void* d_ws, size_t ws_size,
                              hipStream_t stream)
{
  (void)in_sizes; (void)n_in; (void)out_size; (void)d_ws; (void)ws_size;  // d_ws UNUSED: size unknown
  const float* x        = (const float*)d_in[0];
  const int*   mask     = (const int*)d_in[1];
  const float* mha_in_w = (const float*)d_in[2];
  const float* mha_in_b = (const float*)d_in[3];
  const float* mha_out_w= (const float*)d_in[4];
  const float* mha_out_b= (const float*)d_in[5];
  const float* asp_w    = (const float*)d_in[6];
  const float* asp_b    = (const float*)d_in[7];
  const float* opi_w    = (const float*)d_in[8];
  const float* opi_b    = (const float*)d_in[9];
  const float* ia_w     = (const float*)d_in[10];
  const float* ia_b     = (const float*)d_in[11];
  const float* io_w     = (const float*)d_in[12];
  const float* io_b     = (const float*)d_in[13];
  const float* cls_a_w  = (const float*)d_in[26];
  const float* cls_a_b  = (const float*)d_in[27];
  const float* cls_o_w  = (const float*)d_in[28];
  const float* cls_o_b  = (const float*)d_in[29];

  // ---- output layout (fp32 elements, return order). ALL scratch lives in dead d_out regions. ----
  float* out   = (float*)d_out;
  float* o_la  = out;                        // logits_asp [16,1024,3]
  float* o_lo  = out + 49152;                // logits_opi; first 64B double as idx[16] until logits
  float* o_x   = out + 98304;                // x copy (written LAST); scratch region (50.3 MB)
  float* o_se1 = o_x + 12582912;             // se1; scratch: qkv bf16 until scatter
  float* o_se2 = o_se1 + 12582912;           // se2
  float* o_ia  = o_se2 + 12582912;           // imp_asp [16,2]
  float* o_io  = o_ia + 32;
  float* o_e1  = o_io + 32;                  // e1 [16,768]
  float* o_e2  = o_e1 + 12288;

  // attention-phase scratch
  short* x_bf   = (short*)o_x;               // [16384,768] bf16 (o_x[0 .. 6.29M))
  short* ctx_bf = (short*)(o_x + 6291456);   // [16384,768] bf16 (o_x[6.29M .. 12.58M))
  short* qkv_bf = (short*)o_se1;             // [16384,2304] bf16 = 75.5MB, spans se1+part of se2
  short* win_bf = (short*)(o_se1 + 18874368);// [2304,768] bf16
  short* wout_bf= (short*)(o_se1 + 19759104);// [768,768] bf16 (ends < se2 end)
  float* eacc   = o_x;                       // [16,768] fp32 accum (x_bf head; x_bf dead by then)
  int*   idxp   = (int*)o_lo;                // [16] until logits overwrites

  // FFN-phase scratch (all inside o_x; ctx/eacc dead by then)
  short* interbuf = (short*)o_x;             // [2048,3072] bf16
  float* preC     = o_x + 3145728;           // [2048,768] fp32
  short* hb       = (short*)(o_x + 4718592); // [2048,768] bf16 shadow of h chunk
  short* wib      = (short*)(o_x + 5505024); // [2,3072,768] bf16
  short* wob      = (short*)(o_x + 7864320); // [2,768,3072] bf16 (ends at 10.22M < 12.58M)

  float* h1 = o_se1;
  float* h2 = o_se2;

  calc_idx<<<Bb, 256, 0, stream>>>(mask, idxp);

  // bf16 conversions: x + MHA weights
  cvt_bf<<<6144, 256, 0, stream>>>(x, x_bf, 1572864);
  cvt_bf<<<864, 256, 0, stream>>>(mha_in_w, win_bf, 221184);
  cvt_bf<<<288, 256, 0, stream>>>(mha_out_w, wout_bf, 73728);

  // QKV gemm (bf16 out) + flash attention (all 16 batches, one launch)
  gemm_bf<EPI_F32, 1><<<dim3(18, 128), 256, 0, stream>>>(
      x_bf, win_bf, mha_in_b, qkv_bf, 2304, 768);
  flash_attn<<<dim3(16, 4, 16), 256, 0, stream>>>(qkv_bf, idxp, ctx_bf);

  // out-proj with fused mean-over-S -> eacc (x_bf region is dead now)
  hipMemsetAsync(eacc, 0, Bb * Dd * sizeof(float), stream);
  gemm_bf<EPI_MEANACC, 0><<<dim3(6, 128), 256, 0, stream>>>(
      ctx_bf, wout_bf, nullptr, eacc, 768, 768);

  e12_kernel<<<96, 256, 0, stream>>>(eacc, mha_out_b, asp_w, asp_b, opi_w, opi_b,
                                     o_e1, o_e2);
  imp_kernel<<<64, 64, 0, stream>>>(o_e1, o_e2, ia_w, ia_b, io_w, io_b, o_ia, o_io);
  scatter_kernel<<<16384, 256, 0, stream>>>(x, o_e1, o_e2, idxp, h1, h2);

  // decoder stacks in place on h1/h2; per-chunk bf16 shadow + all-bf16 gemms
  for (int st = 0; st < 2; ++st) {
    float* h = st ? h2 : h1;
    const float* Wi = (const float*)d_in[14 + st * 6];
    const float* bi = (const float*)d_in[15 + st * 6];
    const float* Wo = (const float*)d_in[16 + st * 6];
    const float* bo = (const float*)d_in[17 + st * 6];
    const float* lg = (const float*)d_in[18 + st * 6];
    const float* lb = (const float*)d_in[19 + st * 6];
    cvt_bf<<<2304, 256, 0, stream>>>(Wi, wib, 589824);   // [2,3072,768]
    cvt_bf<<<2304, 256, 0, stream>>>(Wo, wob, 589824);   // [2,768,3072]
    for (int c = 0; c < 8; ++c) {
      float* hc = h + (size_t)c * 2048 * Dd;
      cvt_bf<<<768, 256, 0, stream>>>(hc, hb, 196608);   // h chunk -> bf16 shadow
      for (int l = 0; l < 2; ++l) {
        gemm_bf<EPI_GELU, 1><<<dim3(3072 / 128, 2048 / 128), 256, 0, stream>>>(
            hb, wib + (size_t)l * 3072 * 768, bi + l * 3072, interbuf, 3072, 768);
        gemm_bf<EPI_F32, 0><<<dim3(768 / 128, 2048 / 128), 256, 0, stream>>>(
            interbuf, wob + (size_t)l * 768 * 3072, bo + l * 768, preC, 768, 3072);
        ln_kernel<<<2048, 64, 0, stream>>>(preC, hc, hb, lg + l * 768, lb + l * 768);
      }
    }
  }

  logits_kernel<<<32768, 64, 0, stream>>>(h1, h2, cls_a_w, cls_a_b, cls_o_w, cls_o_b,
                                          o_la, o_lo);
  // x copy LAST (o_x served as scratch until here)
  copy16<<<12288, 256, 0, stream>>>((const uint4*)x, (uint4*)o_x, 3145728);
}

// Round 3
// 2458.260 us; speedup vs baseline: 5.0277x; 1.6059x over previous
//
#include <hip/hip_runtime.h>
#include <hip/hip_bf16.h>
#include <stdint.h>

// Problem dims (fixed): B=16 S=1024 D=768 NH=4 hd=192 DFF=3072 NL=2 C=3
#define Bb 16
#define Ss 1024
#define Dd 768
#define HDd 192

typedef __attribute__((ext_vector_type(8))) short short8;   // 8 bf16 (4 VGPRs)
typedef __attribute__((ext_vector_type(4))) short short4a;  // 4 bf16 (2 VGPRs)
typedef __attribute__((ext_vector_type(4))) float f32x4;

__device__ __forceinline__ short f2bf(float f) {
  union { __hip_bfloat16 h; short s; } u;
  u.h = __float2bfloat16(f);
  return u.s;
}
__device__ __forceinline__ short8 cvt8(float4 lo, float4 hi) {
  short8 r;
  r[0] = f2bf(lo.x); r[1] = f2bf(lo.y); r[2] = f2bf(lo.z); r[3] = f2bf(lo.w);
  r[4] = f2bf(hi.x); r[5] = f2bf(hi.y); r[6] = f2bf(hi.z); r[7] = f2bf(hi.w);
  return r;
}
// async global->LDS 16B (m97 staging). LDS dest is wave-uniform base + lane*16:
// per-lane dest pointers must be lane-contiguous within each wave.
__device__ __forceinline__ void gload_lds16(const void* g, void* l) {
  __builtin_amdgcn_global_load_lds(
      (const __attribute__((address_space(1))) void*)g,
      (__attribute__((address_space(3))) void*)l, 16, 0, 0);
}

enum { EPI_F32 = 0, EPI_GELU = 1, EPI_MEANACC = 2, EPI_RES = 3 };

// C[m,n] = sum_k A[m,k]*Bw[n,k] (+bias[n], +epilogue). bf16 operands in global.
// m97 structure, BK=64: global_load_lds width-16 staging, 128x128 tile,
// 32 MFMA per barrier pair. LDS rows are 8x16B units XOR-swizzled by row&7
// (rule 21: linear LDS dest + inverse-swizzled global SOURCE + swizzled read)
// -> frag reads are 2-way (free) instead of 4-row bank aliasing.
// EPI_RES: out[row,col] = acc + bias + out[row,col] (in-place residual, fp32).
// OBF=1 -> store bf16 (consumer is another gemm), else fp32.
template <int EPI, int OBF>
__global__ __launch_bounds__(256) void gemm_bf(
    const short* __restrict__ A, const short* __restrict__ Bw,
    const float* __restrict__ bias, void* __restrict__ outp,
    const int N, const int K)
{
  constexpr int TM = 128, TN = 128, BK = 64;
  __shared__ __align__(16) short As[TM * BK];   // 16 KB
  __shared__ __align__(16) short Bs[TN * BK];   // 16 KB

  const int tid = threadIdx.x;
  const int wave = tid >> 6, lane = tid & 63;
  const int l16 = lane & 15, quad = lane >> 4;
  const int wm = wave >> 1, wn = wave & 1;
  const size_t m0 = (size_t)blockIdx.y * TM;
  const size_t n0 = (size_t)blockIdx.x * TN;

  // staging: 1024 16B-units per matrix; thread stages units tid+256*i (i<4).
  // unit c -> (row=c>>3, physical u=c&7) holding global logical unit u^(row&7).
  // row_i = srow+32i keeps row&7 and u constant across i.
  const int srow = tid >> 3;
  const int sunit = (tid & 7) ^ (srow & 7);
  const short* Ag = A + (m0 + srow) * K + sunit * 8;
  const short* Bg = Bw + (n0 + srow) * K + sunit * 8;
  short* Asd = &As[tid * 8];
  short* Bsd = &Bs[tid * 8];

  f32x4 acc[4][4];
#pragma unroll
  for (int i = 0; i < 4; ++i)
#pragma unroll
    for (int j = 0; j < 4; ++j) acc[i][j] = (f32x4){0.f, 0.f, 0.f, 0.f};

#pragma unroll 1
  for (int k0 = 0; k0 < K; k0 += BK) {
    __syncthreads();                 // WAR: prev iter's LDS reads done
#pragma unroll
    for (int i = 0; i < 4; ++i) {
      gload_lds16(Ag + (size_t)(32 * i) * K + k0, Asd + 2048 * i);
      gload_lds16(Bg + (size_t)(32 * i) * K + k0, Bsd + 2048 * i);
    }
    __syncthreads();                 // RAW: vmcnt drained before barrier

#pragma unroll
    for (int kh = 0; kh < 2; ++kh) {
      short8 af[4], bfr[4];
#pragma unroll
      for (int i = 0; i < 4; ++i) {
        const int arow = wm * 64 + i * 16 + l16;   // arow&7 == l16&7
        const int pu = ((kh * 4 + quad) ^ (l16 & 7)) * 8;
        af[i]  = *(const short8*)&As[arow * BK + pu];
        bfr[i] = *(const short8*)&Bs[(wn * 64 + i * 16 + l16) * BK + pu];
      }
#pragma unroll
      for (int mt = 0; mt < 4; ++mt)
#pragma unroll
        for (int nt = 0; nt < 4; ++nt)
          acc[mt][nt] = __builtin_amdgcn_mfma_f32_16x16x32_bf16(af[mt], bfr[nt], acc[mt][nt], 0, 0, 0);
    }
  }

  if constexpr (EPI == EPI_MEANACC) {
    // fused mean-over-S: column sums -> atomicAdd into [B,D] fp32 accumulator
    float* eacc = (float*)outp;
    const int b = (int)(m0 >> 10);   // 1024 rows per batch; 128-row tiles never straddle
#pragma unroll
    for (int nt = 0; nt < 4; ++nt) {
      float cs = 0.f;
#pragma unroll
      for (int mt = 0; mt < 4; ++mt)
#pragma unroll
        for (int r = 0; r < 4; ++r) cs += acc[mt][nt][r];
      cs += __shfl_xor(cs, 16, 64);
      cs += __shfl_xor(cs, 32, 64);
      if (quad == 0) {
        const int col = (int)n0 + wn * 64 + nt * 16 + l16;
        atomicAdd(&eacc[b * Dd + col], cs);
      }
    }
  } else {
#pragma unroll
    for (int nt = 0; nt < 4; ++nt) {
      const size_t col = n0 + wn * 64 + nt * 16 + l16;
      const float bv = bias[col];
#pragma unroll
      for (int mt = 0; mt < 4; ++mt) {
#pragma unroll
        for (int r = 0; r < 4; ++r) {
          const size_t row = m0 + wm * 64 + mt * 16 + quad * 4 + r;
          float v = acc[mt][nt][r] + bv;
          if constexpr (EPI == EPI_GELU)
            v = 0.5f * v * (1.f + erff(v * 0.70710678118654752f));
          if constexpr (EPI == EPI_RES)
            v += ((float*)outp)[row * N + col];   // in-place residual add
          if constexpr (OBF)
            ((short*)outp)[row * N + col] = f2bf(v);
          else
            ((float*)outp)[row * N + col] = v;
        }
      }
    }
  }
}

// ---- MFMA flash attention on bf16 qkv ---------------------------------------
// grid dim3(4,16,16): x = head, y = batch, z = q-tile. (h,b) fast dims => the
// 16 q-tile blocks sharing one (b,h)'s K/V have flat-index ≡ h+4b (mod 64), so
// they land on ONE XCD (T1 L2 locality: K/V fetched once per XCD, not 8x).
// 4 waves/block, each wave owns 16 q rows. Swapped QK^T; K tile staged via
// global_load_lds with source-side swizzle; V^T via register transpose.
__global__ __launch_bounds__(256, 2) void flash_attn(
    const short* __restrict__ qkv, const int* __restrict__ idxp,
    short* __restrict__ ctx)
{
  __shared__ __align__(16) short Ks[64 * 192];    // 24.0 KB
  __shared__ __align__(16) short Vt[192 * 64];    // 24.0 KB
  __shared__ __align__(16) short Ps[4][16 * 64];  //  8.0 KB (per-wave P)

  const int tid = threadIdx.x, wave = tid >> 6, lane = tid & 63;
  const int l16 = lane & 15, quad = lane >> 4;
  const int h = blockIdx.x, b = blockIdx.y, qt = blockIdx.z;
  const int L = idxp[b] + 1;                      // number of valid keys
  const short* base = qkv + (size_t)b * Ss * (3 * Dd);
  const short* Kb = base + Dd + h * HDd;
  const short* Vb = base + 2 * Dd + h * HDd;

  // Q fragments (MFMA B-operand): direct bf16 loads
  short8 qf[6];
  {
    const short* qp = base + (size_t)(qt * 64 + wave * 16 + l16) * (3 * Dd) + h * HDd;
#pragma unroll
    for (int c = 0; c < 6; ++c) qf[c] = *(const short8*)(qp + c * 32 + quad * 8);
  }

  f32x4 acc[12];                                  // O accum: 16 q x 192 d per wave
#pragma unroll
  for (int i = 0; i < 12; ++i) acc[i] = (f32x4){0.f, 0.f, 0.f, 0.f};
  float m = -3.0e38f, l = 0.f;
  const float scale = 0.07216878364870322f;       // 1/sqrt(192)

#pragma unroll 1
  for (int kt = 0; kt < 16; ++kt) {
    const int k0 = kt * 64;
    if (k0 >= L) break;                           // prefix mask: rest is masked
    __syncthreads();                              // WAR on Ks/Vt

    // stage K tile [64 k][192 hd] via gload_lds; physical 16B-unit (kk,u) holds
    // global unit u^(kk&7) so the swizzled read below lands on logical data
#pragma unroll
    for (int i = 0; i < 6; ++i) {
      const int c = tid + 256 * i;
      const int kk = c / 24, u = c % 24;
      gload_lds16(Kb + (size_t)(k0 + kk) * (3 * Dd) + (u ^ (kk & 7)) * 8, &Ks[c * 8]);
    }
    // stage V^T tile [192 d][64 k]: pack (k,k+1) bf16 pairs, swizzled
#pragma unroll
    for (int i = 0; i < 6; ++i) {
      const int c = tid + 256 * i;
      const int kp2 = (c & 31) * 2, dc = (c >> 5) * 4;
      const short* vp = Vb + (size_t)(k0 + kp2) * (3 * Dd) + dc;
      const short4a va  = *(const short4a*)vp;
      const short4a vb4 = *(const short4a*)(vp + 3 * Dd);
#pragma unroll
      for (int j = 0; j < 4; ++j) {
        const int d = dc + j;
        const unsigned int pr = (unsigned int)(unsigned short)va[j] |
                                ((unsigned int)(unsigned short)vb4[j] << 16);
        *(unsigned int*)&Vt[(d * 64 + kp2) ^ ((d & 7) << 3)] = pr;
      }
    }
    __syncthreads();                              // RAW (vmcnt+lgkm drained)

    // S^T tile [64 k][16 q] = K·Q^T
    f32x4 accS[4];
#pragma unroll
    for (int mt = 0; mt < 4; ++mt) accS[mt] = (f32x4){0.f, 0.f, 0.f, 0.f};
#pragma unroll
    for (int c = 0; c < 6; ++c) {
      short8 kf[4];
#pragma unroll
      for (int mt = 0; mt < 4; ++mt) {
        const int row = mt * 16 + l16;
        kf[mt] = *(const short8*)&Ks[(row * 192 + c * 32 + quad * 8) ^ ((l16 & 7) << 3)];
      }
#pragma unroll
      for (int mt = 0; mt < 4; ++mt)
        accS[mt] = __builtin_amdgcn_mfma_f32_16x16x32_bf16(kf[mt], qf[c], accS[mt], 0, 0, 0);
    }

    // lane holds k = k0 + mt*16 + quad*4 + r for q = l16 : scale + padding mask
    float tm = -3.0e38f;
#pragma unroll
    for (int mt = 0; mt < 4; ++mt) {
      const int kg = k0 + mt * 16 + quad * 4;
#pragma unroll
      for (int r = 0; r < 4; ++r) {
        const float sv = (kg + r < L) ? accS[mt][r] * scale : -1.0e30f;
        accS[mt][r] = sv;
        tm = fmaxf(tm, sv);
      }
    }
    tm = fmaxf(tm, __shfl_xor(tm, 16));
    tm = fmaxf(tm, __shfl_xor(tm, 32));
    const float mn = fmaxf(m, tm);
    const bool stay = (mn == m);
    const float sf = __expf(m - mn);
    m = mn;
    l *= sf;

    float rs = 0.f;
#pragma unroll
    for (int mt = 0; mt < 4; ++mt) {
      short4a pw;
#pragma unroll
      for (int r = 0; r < 4; ++r) {
        const float p = __expf(accS[mt][r] - mn);
        rs += p;
        pw[r] = f2bf(p);
      }
      *(short4a*)&Ps[wave][(l16 * 64 + mt * 16 + quad * 4) ^ ((l16 & 7) << 3)] = pw;
    }
    rs += __shfl_xor(rs, 16);
    rs += __shfl_xor(rs, 32);
    l += rs;

    if (!__all(stay)) {                           // defer-rescale (T13)
      f32x4 sv_;
#pragma unroll
      for (int r = 0; r < 4; ++r) sv_[r] = __shfl(sf, quad * 4 + r);
#pragma unroll
      for (int nt = 0; nt < 12; ++nt)
#pragma unroll
        for (int r = 0; r < 4; ++r) acc[nt][r] *= sv_[r];
    }

    // O += P·V
#pragma unroll
    for (int ks = 0; ks < 2; ++ks) {
      const short8 pa =
          *(const short8*)&Ps[wave][(l16 * 64 + ks * 32 + quad * 8) ^ ((l16 & 7) << 3)];
#pragma unroll
      for (int nt = 0; nt < 12; ++nt) {
        const int d = nt * 16 + l16;
        const short8 vb =
            *(const short8*)&Vt[(d * 64 + ks * 32 + quad * 8) ^ ((d & 7) << 3)];
        acc[nt] = __builtin_amdgcn_mfma_f32_16x16x32_bf16(pa, vb, acc[nt], 0, 0, 0);
      }
    }
  }

  // epilogue: normalize and write ctx[b, q, h*192 + d] as bf16
  const float inv = 1.f / l;
  f32x4 iv;
#pragma unroll
  for (int r = 0; r < 4; ++r) iv[r] = __shfl(inv, quad * 4 + r);
  const int qrow = qt * 64 + wave * 16;
#pragma unroll
  for (int r = 0; r < 4; ++r) {
    short* cp = ctx + ((size_t)b * Ss + qrow + quad * 4 + r) * Dd + h * HDd + l16;
#pragma unroll
    for (int nt = 0; nt < 12; ++nt) cp[nt * 16] = f2bf(acc[nt][r] * iv[r]);
  }
}

__global__ __launch_bounds__(256) void calc_idx(const int* __restrict__ mask, int* __restrict__ idx) {
  __shared__ int sm[256];
  const int b = blockIdx.x, tid = threadIdx.x;
  int s = 0;
  for (int i = tid; i < Ss; i += 256) s += mask[b * Ss + i];
  sm[tid] = s;
  __syncthreads();
  for (int o = 128; o > 0; o >>= 1) {
    if (tid < o) sm[tid] += sm[tid + o];
    __syncthreads();
  }
  if (tid == 0) idx[b] = sm[0] - 1;
}

// fp32 -> bf16, 8 elems/thread
__global__ __launch_bounds__(256) void cvt_bf(const float* __restrict__ s,
                                              short* __restrict__ d, int n8) {
  const int i = blockIdx.x * 256 + threadIdx.x;
  if (i < n8)
    *(short8*)(d + (size_t)i * 8) = cvt8(((const float4*)s)[i * 2],
                                         ((const float4*)s)[i * 2 + 1]);
}

// e1/e2: one thread per (which,n,b). 16-lane groups share a w-row (broadcast loads).
// emb[b][d] = eacc[b][d]/1024 + outb[d] recomputed in-flight (trivial FLOPs).
__global__ __launch_bounds__(256) void e12_kernel(
    const float* __restrict__ eacc, const float* __restrict__ outb,
    const float* __restrict__ aw, const float* __restrict__ ab,
    const float* __restrict__ ow, const float* __restrict__ ob,
    float* __restrict__ e1, float* __restrict__ e2)
{
  const int id = blockIdx.x * 256 + threadIdx.x;  // 0..24575
  const int which = (id >= 12288);
  const int r = which ? id - 12288 : id;
  const int n = r >> 4, b = r & 15;
  const float* w = (which ? ow : aw) + (size_t)n * Dd;
  const float* ea = eacc + b * Dd;
  float s = 0.f;
#pragma unroll 4
  for (int d = 0; d < Dd; d += 4) {
    const float4 wv = *(const float4*)(w + d);
    const float4 ev = *(const float4*)(ea + d);
    const float4 bv = *(const float4*)(outb + d);
    s += (ev.x * (1.f / 1024.f) + bv.x) * wv.x + (ev.y * (1.f / 1024.f) + bv.y) * wv.y
       + (ev.z * (1.f / 1024.f) + bv.z) * wv.z + (ev.w * (1.f / 1024.f) + bv.w) * wv.w;
  }
  s += which ? ob[n] : ab[n];
  (which ? e2 : e1)[b * Dd + n] = s;
}

__global__ __launch_bounds__(64) void imp_kernel(
    const float* __restrict__ e1, const float* __restrict__ e2,
    const float* __restrict__ wa, const float* __restrict__ ba,
    const float* __restrict__ wo, const float* __restrict__ bo,
    float* __restrict__ outa, float* __restrict__ outo)
{
  const int id = blockIdx.x, lane = threadIdx.x;
  const int b = id >> 2, which = (id >> 1) & 1, c = id & 1;
  const float* e = which ? e2 : e1;
  const float* w = which ? wo : wa;
  const float* bb = which ? bo : ba;
  float s = 0.f;
  for (int d = lane; d < Dd; d += 64) s += e[b * Dd + d] * w[c * Dd + d];
  for (int off = 32; off > 0; off >>= 1) s += __shfl_xor(s, off, 64);
  if (lane == 0) {
    float* o = which ? outo : outa;
    o[b * 2 + c] = s + bb[c];
  }
}

// se1: row0<-e1 then row idx<-e2 ; se2: row idx<-e2 then row0<-e1
__global__ __launch_bounds__(256) void scatter_kernel(
    const float* __restrict__ x, const float* __restrict__ e1,
    const float* __restrict__ e2, const int* __restrict__ idx,
    float* __restrict__ h1, float* __restrict__ h2)
{
  const int row = blockIdx.x;
  const int b = row >> 10, s = row & 1023;
  const int ix = idx[b];
  const size_t base = (size_t)row * Dd;
  for (int i = threadIdx.x; i < Dd; i += 256) {
    const float xv = x[base + i];
    const float v1 = e1[b * Dd + i];
    const float v2 = e2[b * Dd + i];
    h1[base + i] = (s == ix) ? v2 : ((s == 0) ? v1 : xv);
    h2[base + i] = (s == 0) ? v1 : ((s == ix) ? v2 : xv);
  }
}

// h already holds FFN_out + residual (EPI_RES). LayerNorm in place + bf16 shadow.
__global__ __launch_bounds__(64) void ln_kernel(
    float* __restrict__ h, short* __restrict__ hb,
    const float* __restrict__ g, const float* __restrict__ bb)
{
  const int row = blockIdx.x, lane = threadIdx.x;
  const size_t base = (size_t)row * Dd;
  float v[12];
  float s = 0.f, sq = 0.f;
#pragma unroll
  for (int t = 0; t < 12; ++t) {
    const int i = t * 64 + lane;
    const float val = h[base + i];
    v[t] = val;
    s += val;
    sq += val * val;
  }
#pragma unroll
  for (int off = 32; off > 0; off >>= 1) {
    s += __shfl_xor(s, off, 64);
    sq += __shfl_xor(sq, off, 64);
  }
  const float m = s * (1.f / 768.f);
  float var = sq * (1.f / 768.f) - m * m;
  var = fmaxf(var, 0.f);
  const float r = rsqrtf(var + 1e-12f);
#pragma unroll
  for (int t = 0; t < 12; ++t) {
    const int i = t * 64 + lane;
    const float o = (v[t] - m) * r * g[i] + bb[i];
    h[base + i] = o;
    hb[base + i] = f2bf(o);
  }
}

// logits[row,0..2] = h[row,:]@w[c,:] + b[c]; blocks 0..16383 -> asp(h1), rest -> opi(h2)
__global__ __launch_bounds__(64) void logits_kernel(
    const float* __restrict__ h1, const float* __restrict__ h2,
    const float* __restrict__ wa, const float* __restrict__ ba,
    const float* __restrict__ wo, const float* __restrict__ bo,
    float* __restrict__ outa, float* __restrict__ outo)
{
  const int id = blockIdx.x, lane = threadIdx.x;
  const int which = id >> 14;
  const int row = id & 16383;
  const float* h = which ? h2 : h1;
  const float* w = which ? wo : wa;
  const float* bc = which ? bo : ba;
  const size_t base = (size_t)row * Dd;
  float s0 = 0.f, s1 = 0.f, s2 = 0.f;
#pragma unroll
  for (int t = 0; t < 12; ++t) {
    const int i = t * 64 + lane;
    const float hv = h[base + i];
    s0 += hv * w[i];
    s1 += hv * w[Dd + i];
    s2 += hv * w[2 * Dd + i];
  }
#pragma unroll
  for (int off = 32; off > 0; off >>= 1) {
    s0 += __shfl_xor(s0, off, 64);
    s1 += __shfl_xor(s1, off, 64);
    s2 += __shfl_xor(s2, off, 64);
  }
  if (lane == 0) {
    float* o = which ? outo : outa;
    o[(size_t)row * 3 + 0] = s0 + bc[0];
    o[(size_t)row * 3 + 1] = s1 + bc[1];
    o[(size_t)row * 3 + 2] = s2 + bc[2];
  }
}

__global__ __launch_bounds__(256) void copy16(const uint4* __restrict__ s, uint4* __restrict__ d, int n) {
  const int i = blockIdx.x * 256 + threadIdx.x;
  if (i < n) d[i] = s[i];
}

extern "C" void kernel_launch(void* const* d_in, const int* in_sizes, int n_in,
                              void* d_out, int out_size, void* d_ws, size_t ws_size,
                              hipStream_t stream)
{
  (void)in_sizes; (void)n_in; (void)out_size; (void)d_ws; (void)ws_size;  // d_ws UNUSED: size unknown
  const float* x        = (const float*)d_in[0];
  const int*   mask     = (const int*)d_in[1];
  const float* mha_in_w = (const float*)d_in[2];
  const float* mha_in_b = (const float*)d_in[3];
  const float* mha_out_w= (const float*)d_in[4];
  const float* mha_out_b= (const float*)d_in[5];
  const float* asp_w    = (const float*)d_in[6];
  const float* asp_b    = (const float*)d_in[7];
  const float* opi_w    = (const float*)d_in[8];
  const float* opi_b    = (const float*)d_in[9];
  const float* ia_w     = (const float*)d_in[10];
  const float* ia_b     = (const float*)d_in[11];
  const float* io_w     = (const float*)d_in[12];
  const float* io_b     = (const float*)d_in[13];
  const float* cls_a_w  = (const float*)d_in[26];
  const float* cls_a_b  = (const float*)d_in[27];
  const float* cls_o_w  = (const float*)d_in[28];
  const float* cls_o_b  = (const float*)d_in[29];

  // ---- output layout (fp32 elements, return order). ALL scratch lives in dead d_out regions. ----
  float* out   = (float*)d_out;
  float* o_la  = out;                        // logits_asp [16,1024,3]
  float* o_lo  = out + 49152;                // logits_opi; first 64B double as idx[16] until logits
  float* o_x   = out + 98304;                // x copy (written LAST); scratch region (50.33 MB)
  float* o_se1 = o_x + 12582912;             // se1; scratch: qkv bf16 until scatter
  float* o_se2 = o_se1 + 12582912;           // se2
  float* o_ia  = o_se2 + 12582912;           // imp_asp [16,2]
  float* o_io  = o_ia + 32;
  float* o_e1  = o_io + 32;                  // e1 [16,768]
  float* o_e2  = o_e1 + 12288;

  // attention-phase scratch
  short* x_bf   = (short*)o_x;               // [16384,768] bf16 (o_x floats [0 .. 6291456))
  short* ctx_bf = (short*)(o_x + 6291456);   // [16384,768] bf16 (floats [6291456 .. 12582912))
  short* qkv_bf = (short*)o_se1;             // [16384,2304] bf16 = 75.5MB, spans se1+part of se2
  short* win_bf = (short*)(o_se1 + 18874368);// [2304,768] bf16
  short* wout_bf= (short*)(o_se1 + 19759104);// [768,768] bf16 (ends < se2 end)
  float* eacc   = o_x;                       // [16,768] fp32 accum (x_bf head; x_bf dead by then)
  int*   idxp   = (int*)o_lo;                // [16] until logits overwrites

  // FFN-phase scratch (exact fit in o_x = 50,331,648 B; ctx_bf dead by then):
  //   interbuf [4096,3072] bf16 = 25,165,824 B   @ float-offset 0
  //   hb       [4096, 768] bf16 =  6,291,456 B   @ 6291456
  //   wib      [2,3072,768] bf16 = 9,437,184 B   @ 7864320
  //   wob      [2,768,3072] bf16 = 9,437,184 B   @ 10223616  (ends 12582912 ✓)
  short* interbuf = (short*)o_x;
  short* hb       = (short*)(o_x + 6291456);
  short* wib      = (short*)(o_x + 7864320);
  short* wob      = (short*)(o_x + 10223616);

  float* h1 = o_se1;
  float* h2 = o_se2;

  calc_idx<<<Bb, 256, 0, stream>>>(mask, idxp);

  // bf16 conversions: x + MHA weights
  cvt_bf<<<6144, 256, 0, stream>>>(x, x_bf, 1572864);
  cvt_bf<<<864, 256, 0, stream>>>(mha_in_w, win_bf, 221184);
  cvt_bf<<<288, 256, 0, stream>>>(mha_out_w, wout_bf, 73728);

  // QKV gemm (bf16 out) + flash attention (all 16 batches, one launch)
  gemm_bf<EPI_F32, 1><<<dim3(18, 128), 256, 0, stream>>>(
      x_bf, win_bf, mha_in_b, qkv_bf, 2304, 768);
  flash_attn<<<dim3(4, 16, 16), 256, 0, stream>>>(qkv_bf, idxp, ctx_bf);

  // out-proj with fused mean-over-S -> eacc (x_bf region is dead now)
  hipMemsetAsync(eacc, 0, Bb * Dd * sizeof(float), stream);
  gemm_bf<EPI_MEANACC, 0><<<dim3(6, 128), 256, 0, stream>>>(
      ctx_bf, wout_bf, nullptr, eacc, 768, 768);

  e12_kernel<<<96, 256, 0, stream>>>(eacc, mha_out_b, asp_w, asp_b, opi_w, opi_b,
                                     o_e1, o_e2);
  imp_kernel<<<64, 64, 0, stream>>>(o_e1, o_e2, ia_w, ia_b, io_w, io_b, o_ia, o_io);
  scatter_kernel<<<16384, 256, 0, stream>>>(x, o_e1, o_e2, idxp, h1, h2);

  // decoder stacks in place on h1/h2. Super-chunks of 4096 rows:
  //   gelu gemm grid (24,32)=768 blocks, out gemm grid (6,32)=192 blocks with
  //   in-place residual epilogue (no preC), then 1-buffer LN + bf16 shadow.
  for (int st = 0; st < 2; ++st) {
    float* h = st ? h2 : h1;
    const float* Wi = (const float*)d_in[14 + st * 6];
    const float* bi = (const float*)d_in[15 + st * 6];
    const float* Wo = (const float*)d_in[16 + st * 6];
    const float* bo = (const float*)d_in[17 + st * 6];
    const float* lg = (const float*)d_in[18 + st * 6];
    const float* lb = (const float*)d_in[19 + st * 6];
    cvt_bf<<<2304, 256, 0, stream>>>(Wi, wib, 589824);   // [2,3072,768]
    cvt_bf<<<2304, 256, 0, stream>>>(Wo, wob, 589824);   // [2,768,3072]
    for (int c = 0; c < 4; ++c) {
      float* hc = h + (size_t)c * 4096 * Dd;
      cvt_bf<<<1536, 256, 0, stream>>>(hc, hb, 393216);  // h super-chunk -> bf16
      for (int l = 0; l < 2; ++l) {
        gemm_bf<EPI_GELU, 1><<<dim3(3072 / 128, 4096 / 128), 256, 0, stream>>>(
            hb, wib + (size_t)l * 3072 * 768, bi + l * 3072, interbuf, 3072, 768);
        gemm_bf<EPI_RES, 0><<<dim3(768 / 128, 4096 / 128), 256, 0, stream>>>(
            interbuf, wob + (size_t)l * 768 * 3072, bo + l * 768, hc, 768, 3072);
        ln_kernel<<<4096, 64, 0, stream>>>(hc, hb, lg + l * 768, lb + l * 768);
      }
    }
  }

  logits_kernel<<<32768, 64, 0, stream>>>(h1, h2, cls_a_w, cls_a_b, cls_o_w, cls_o_b,
                                          o_la, o_lo);
  // x copy LAST (o_x served as scratch until here)
  copy16<<<12288, 256, 0, stream>>>((const uint4*)x, (uint4*)o_x, 3145728);
}

// Round 4
// 2253.955 us; speedup vs baseline: 5.4834x; 1.0906x over previous
//
#include <hip/hip_runtime.h>
#include <hip/hip_bf16.h>
#include <stdint.h>

// Problem dims (fixed): B=16 S=1024 D=768 NH=4 hd=192 DFF=3072 NL=2 C=3
#define Bb 16
#define Ss 1024
#define Dd 768
#define HDd 192

typedef __attribute__((ext_vector_type(8))) short short8;   // 8 bf16 (4 VGPRs)
typedef __attribute__((ext_vector_type(4))) short short4a;  // 4 bf16 (2 VGPRs)
typedef __attribute__((ext_vector_type(4))) float f32x4;

__device__ __forceinline__ short f2bf(float f) {
  union { __hip_bfloat16 h; short s; } u;
  u.h = __float2bfloat16(f);
  return u.s;
}
__device__ __forceinline__ short8 cvt8(float4 lo, float4 hi) {
  short8 r;
  r[0] = f2bf(lo.x); r[1] = f2bf(lo.y); r[2] = f2bf(lo.z); r[3] = f2bf(lo.w);
  r[4] = f2bf(hi.x); r[5] = f2bf(hi.y); r[6] = f2bf(hi.z); r[7] = f2bf(hi.w);
  return r;
}
// async global->LDS 16B (m97 staging). LDS dest is wave-uniform base + lane*16:
// per-lane dest pointers must be lane-contiguous within each wave.
__device__ __forceinline__ void gload_lds16(const void* g, void* l) {
  __builtin_amdgcn_global_load_lds(
      (const __attribute__((address_space(1))) void*)g,
      (__attribute__((address_space(3))) void*)l, 16, 0, 0);
}

enum { EPI_F32 = 0, EPI_GELU = 1, EPI_MEANACC = 2, EPI_RESAT = 3 };

// C[m,n] = sum_k A[m,k]*Bw[n,k] (+bias[n], +epilogue). bf16 operands in global.
// m97 structure, BK=64: global_load_lds width-16 staging, 128x128 tile,
// 32 MFMA per barrier pair. LDS rows are 8x16B units XOR-swizzled by row&7
// (rule 21: linear LDS dest + inverse-swizzled global SOURCE + swizzled read).
// EPI_RESAT: split-K over blockIdx.z (4 quarters); partial sums atomicAdd into
// out (which pre-holds the residual); bias contributed by the kz==0 block only.
// OBF=1 -> store bf16 (consumer is another gemm), else fp32.
template <int EPI, int OBF>
__global__ __launch_bounds__(256) void gemm_bf(
    const short* __restrict__ A, const short* __restrict__ Bw,
    const float* __restrict__ bias, void* __restrict__ outp,
    const int N, const int K)
{
  constexpr int TM = 128, TN = 128, BK = 64;
  __shared__ __align__(16) short As[TM * BK];   // 16 KB
  __shared__ __align__(16) short Bs[TN * BK];   // 16 KB

  const int tid = threadIdx.x;
  const int wave = tid >> 6, lane = tid & 63;
  const int l16 = lane & 15, quad = lane >> 4;
  const int wm = wave >> 1, wn = wave & 1;
  const size_t m0 = (size_t)blockIdx.y * TM;
  const size_t n0 = (size_t)blockIdx.x * TN;
  const int kz = blockIdx.z;                     // split-K index (EPI_RESAT)
  const int kbeg = (EPI == EPI_RESAT) ? kz * (K >> 2) : 0;
  const int kend = (EPI == EPI_RESAT) ? kbeg + (K >> 2) : K;

  // staging: 1024 16B-units per matrix; thread stages units tid+256*i (i<4).
  // unit c -> (row=c>>3, physical u=c&7) holding global logical unit u^(row&7).
  // row_i = srow+32i keeps row&7 and u constant across i.
  const int srow = tid >> 3;
  const int sunit = (tid & 7) ^ (srow & 7);
  const short* Ag = A + (m0 + srow) * K + sunit * 8;
  const short* Bg = Bw + (n0 + srow) * K + sunit * 8;
  short* Asd = &As[tid * 8];
  short* Bsd = &Bs[tid * 8];

  f32x4 acc[4][4];
#pragma unroll
  for (int i = 0; i < 4; ++i)
#pragma unroll
    for (int j = 0; j < 4; ++j) acc[i][j] = (f32x4){0.f, 0.f, 0.f, 0.f};

#pragma unroll 1
  for (int k0 = kbeg; k0 < kend; k0 += BK) {
    __syncthreads();                 // WAR: prev iter's LDS reads done
#pragma unroll
    for (int i = 0; i < 4; ++i) {
      gload_lds16(Ag + (size_t)(32 * i) * K + k0, Asd + 2048 * i);
      gload_lds16(Bg + (size_t)(32 * i) * K + k0, Bsd + 2048 * i);
    }
    __syncthreads();                 // RAW: vmcnt drained before barrier

#pragma unroll
    for (int kh = 0; kh < 2; ++kh) {
      short8 af[4], bfr[4];
#pragma unroll
      for (int i = 0; i < 4; ++i) {
        const int arow = wm * 64 + i * 16 + l16;   // arow&7 == l16&7
        const int pu = ((kh * 4 + quad) ^ (l16 & 7)) * 8;
        af[i]  = *(const short8*)&As[arow * BK + pu];
        bfr[i] = *(const short8*)&Bs[(wn * 64 + i * 16 + l16) * BK + pu];
      }
#pragma unroll
      for (int mt = 0; mt < 4; ++mt)
#pragma unroll
        for (int nt = 0; nt < 4; ++nt)
          acc[mt][nt] = __builtin_amdgcn_mfma_f32_16x16x32_bf16(af[mt], bfr[nt], acc[mt][nt], 0, 0, 0);
    }
  }

  if constexpr (EPI == EPI_MEANACC) {
    // fused mean-over-S: column sums -> atomicAdd into [B,D] fp32 accumulator
    float* eacc = (float*)outp;
    const int b = (int)(m0 >> 10);   // 1024 rows per batch; 128-row tiles never straddle
#pragma unroll
    for (int nt = 0; nt < 4; ++nt) {
      float cs = 0.f;
#pragma unroll
      for (int mt = 0; mt < 4; ++mt)
#pragma unroll
        for (int r = 0; r < 4; ++r) cs += acc[mt][nt][r];
      cs += __shfl_xor(cs, 16, 64);
      cs += __shfl_xor(cs, 32, 64);
      if (quad == 0) {
        const int col = (int)n0 + wn * 64 + nt * 16 + l16;
        atomicAdd(&eacc[b * Dd + col], cs);
      }
    }
  } else if constexpr (EPI == EPI_RESAT) {
    // split-K partial: atomicAdd into out (pre-holds residual h)
    float* outf = (float*)outp;
#pragma unroll
    for (int nt = 0; nt < 4; ++nt) {
      const size_t col = n0 + wn * 64 + nt * 16 + l16;
      const float bv = (kz == 0) ? bias[col] : 0.f;
#pragma unroll
      for (int mt = 0; mt < 4; ++mt) {
#pragma unroll
        for (int r = 0; r < 4; ++r) {
          const size_t row = m0 + wm * 64 + mt * 16 + quad * 4 + r;
          atomicAdd(&outf[row * N + col], acc[mt][nt][r] + bv);
        }
      }
    }
  } else {
#pragma unroll
    for (int nt = 0; nt < 4; ++nt) {
      const size_t col = n0 + wn * 64 + nt * 16 + l16;
      const float bv = bias[col];
#pragma unroll
      for (int mt = 0; mt < 4; ++mt) {
#pragma unroll
        for (int r = 0; r < 4; ++r) {
          const size_t row = m0 + wm * 64 + mt * 16 + quad * 4 + r;
          float v = acc[mt][nt][r] + bv;
          if constexpr (EPI == EPI_GELU)
            v = 0.5f * v * (1.f + erff(v * 0.70710678118654752f));
          if constexpr (OBF)
            ((short*)outp)[row * N + col] = f2bf(v);
          else
            ((float*)outp)[row * N + col] = v;
        }
      }
    }
  }
}

// ---- MFMA flash attention on bf16 qkv ---------------------------------------
// grid dim3(16,4,16): x = q-tile, y = head, z = batch (qt-fast: spreads each
// (b,h)'s q-tiles across XCDs. The XCD-pinned variant cut FETCH 163->51MB but
// ran 8% SLOWER (R3): not HBM-bound, and pinning serialized K/V behind one L2).
// 4 waves/block, each wave owns 16 q rows. Swapped QK^T; K tile staged via
// global_load_lds with source-side swizzle; V^T via register transpose.
__global__ __launch_bounds__(256, 2) void flash_attn(
    const short* __restrict__ qkv, const int* __restrict__ idxp,
    short* __restrict__ ctx)
{
  __shared__ __align__(16) short Ks[64 * 192];    // 24.0 KB
  __shared__ __align__(16) short Vt[192 * 64];    // 24.0 KB
  __shared__ __align__(16) short Ps[4][16 * 64];  //  8.0 KB (per-wave P)

  const int tid = threadIdx.x, wave = tid >> 6, lane = tid & 63;
  const int l16 = lane & 15, quad = lane >> 4;
  const int qt = blockIdx.x, h = blockIdx.y, b = blockIdx.z;
  const int L = idxp[b] + 1;                      // number of valid keys
  const short* base = qkv + (size_t)b * Ss * (3 * Dd);
  const short* Kb = base + Dd + h * HDd;
  const short* Vb = base + 2 * Dd + h * HDd;

  // Q fragments (MFMA B-operand): direct bf16 loads
  short8 qf[6];
  {
    const short* qp = base + (size_t)(qt * 64 + wave * 16 + l16) * (3 * Dd) + h * HDd;
#pragma unroll
    for (int c = 0; c < 6; ++c) qf[c] = *(const short8*)(qp + c * 32 + quad * 8);
  }

  f32x4 acc[12];                                  // O accum: 16 q x 192 d per wave
#pragma unroll
  for (int i = 0; i < 12; ++i) acc[i] = (f32x4){0.f, 0.f, 0.f, 0.f};
  float m = -3.0e38f, l = 0.f;
  const float scale = 0.07216878364870322f;       // 1/sqrt(192)

#pragma unroll 1
  for (int kt = 0; kt < 16; ++kt) {
    const int k0 = kt * 64;
    if (k0 >= L) break;                           // prefix mask: rest is masked
    __syncthreads();                              // WAR on Ks/Vt

    // stage K tile [64 k][192 hd] via gload_lds; physical 16B-unit (kk,u) holds
    // global unit u^(kk&7) so the swizzled read below lands on logical data
#pragma unroll
    for (int i = 0; i < 6; ++i) {
      const int c = tid + 256 * i;
      const int kk = c / 24, u = c % 24;
      gload_lds16(Kb + (size_t)(k0 + kk) * (3 * Dd) + (u ^ (kk & 7)) * 8, &Ks[c * 8]);
    }
    // stage V^T tile [192 d][64 k]: pack (k,k+1) bf16 pairs, swizzled
#pragma unroll
    for (int i = 0; i < 6; ++i) {
      const int c = tid + 256 * i;
      const int kp2 = (c & 31) * 2, dc = (c >> 5) * 4;
      const short* vp = Vb + (size_t)(k0 + kp2) * (3 * Dd) + dc;
      const short4a va  = *(const short4a*)vp;
      const short4a vb4 = *(const short4a*)(vp + 3 * Dd);
#pragma unroll
      for (int j = 0; j < 4; ++j) {
        const int d = dc + j;
        const unsigned int pr = (unsigned int)(unsigned short)va[j] |
                                ((unsigned int)(unsigned short)vb4[j] << 16);
        *(unsigned int*)&Vt[(d * 64 + kp2) ^ ((d & 7) << 3)] = pr;
      }
    }
    __syncthreads();                              // RAW (vmcnt+lgkm drained)

    // S^T tile [64 k][16 q] = K·Q^T
    f32x4 accS[4];
#pragma unroll
    for (int mt = 0; mt < 4; ++mt) accS[mt] = (f32x4){0.f, 0.f, 0.f, 0.f};
#pragma unroll
    for (int c = 0; c < 6; ++c) {
      short8 kf[4];
#pragma unroll
      for (int mt = 0; mt < 4; ++mt) {
        const int row = mt * 16 + l16;
        kf[mt] = *(const short8*)&Ks[(row * 192 + c * 32 + quad * 8) ^ ((l16 & 7) << 3)];
      }
#pragma unroll
      for (int mt = 0; mt < 4; ++mt)
        accS[mt] = __builtin_amdgcn_mfma_f32_16x16x32_bf16(kf[mt], qf[c], accS[mt], 0, 0, 0);
    }

    // lane holds k = k0 + mt*16 + quad*4 + r for q = l16 : scale + padding mask
    float tm = -3.0e38f;
#pragma unroll
    for (int mt = 0; mt < 4; ++mt) {
      const int kg = k0 + mt * 16 + quad * 4;
#pragma unroll
      for (int r = 0; r < 4; ++r) {
        const float sv = (kg + r < L) ? accS[mt][r] * scale : -1.0e30f;
        accS[mt][r] = sv;
        tm = fmaxf(tm, sv);
      }
    }
    tm = fmaxf(tm, __shfl_xor(tm, 16));
    tm = fmaxf(tm, __shfl_xor(tm, 32));
    const float mn = fmaxf(m, tm);
    const bool stay = (mn == m);
    const float sf = __expf(m - mn);
    m = mn;
    l *= sf;

    float rs = 0.f;
#pragma unroll
    for (int mt = 0; mt < 4; ++mt) {
      short4a pw;
#pragma unroll
      for (int r = 0; r < 4; ++r) {
        const float p = __expf(accS[mt][r] - mn);
        rs += p;
        pw[r] = f2bf(p);
      }
      *(short4a*)&Ps[wave][(l16 * 64 + mt * 16 + quad * 4) ^ ((l16 & 7) << 3)] = pw;
    }
    rs += __shfl_xor(rs, 16);
    rs += __shfl_xor(rs, 32);
    l += rs;

    if (!__all(stay)) {                           // defer-rescale (T13)
      f32x4 sv_;
#pragma unroll
      for (int r = 0; r < 4; ++r) sv_[r] = __shfl(sf, quad * 4 + r);
#pragma unroll
      for (int nt = 0; nt < 12; ++nt)
#pragma unroll
        for (int r = 0; r < 4; ++r) acc[nt][r] *= sv_[r];
    }

    // O += P·V
#pragma unroll
    for (int ks = 0; ks < 2; ++ks) {
      const short8 pa =
          *(const short8*)&Ps[wave][(l16 * 64 + ks * 32 + quad * 8) ^ ((l16 & 7) << 3)];
#pragma unroll
      for (int nt = 0; nt < 12; ++nt) {
        const int d = nt * 16 + l16;
        const short8 vb =
            *(const short8*)&Vt[(d * 64 + ks * 32 + quad * 8) ^ ((d & 7) << 3)];
        acc[nt] = __builtin_amdgcn_mfma_f32_16x16x32_bf16(pa, vb, acc[nt], 0, 0, 0);
      }
    }
  }

  // epilogue: normalize and write ctx[b, q, h*192 + d] as bf16
  const float inv = 1.f / l;
  f32x4 iv;
#pragma unroll
  for (int r = 0; r < 4; ++r) iv[r] = __shfl(inv, quad * 4 + r);
  const int qrow = qt * 64 + wave * 16;
#pragma unroll
  for (int r = 0; r < 4; ++r) {
    short* cp = ctx + ((size_t)b * Ss + qrow + quad * 4 + r) * Dd + h * HDd + l16;
#pragma unroll
    for (int nt = 0; nt < 12; ++nt) cp[nt * 16] = f2bf(acc[nt][r] * iv[r]);
  }
}

__global__ __launch_bounds__(256) void calc_idx(const int* __restrict__ mask, int* __restrict__ idx) {
  __shared__ int sm[256];
  const int b = blockIdx.x, tid = threadIdx.x;
  int s = 0;
  for (int i = tid; i < Ss; i += 256) s += mask[b * Ss + i];
  sm[tid] = s;
  __syncthreads();
  for (int o = 128; o > 0; o >>= 1) {
    if (tid < o) sm[tid] += sm[tid + o];
    __syncthreads();
  }
  if (tid == 0) idx[b] = sm[0] - 1;
}

// fp32 -> bf16, 8 elems/thread
__global__ __launch_bounds__(256) void cvt_bf(const float* __restrict__ s,
                                              short* __restrict__ d, int n8) {
  const int i = blockIdx.x * 256 + threadIdx.x;
  if (i < n8)
    *(short8*)(d + (size_t)i * 8) = cvt8(((const float4*)s)[i * 2],
                                         ((const float4*)s)[i * 2 + 1]);
}

// e1/e2: one thread per (which,n,b). 16-lane groups share a w-row (broadcast loads).
// emb[b][d] = eacc[b][d]/1024 + outb[d] recomputed in-flight (trivial FLOPs).
__global__ __launch_bounds__(256) void e12_kernel(
    const float* __restrict__ eacc, const float* __restrict__ outb,
    const float* __restrict__ aw, const float* __restrict__ ab,
    const float* __restrict__ ow, const float* __restrict__ ob,
    float* __restrict__ e1, float* __restrict__ e2)
{
  const int id = blockIdx.x * 256 + threadIdx.x;  // 0..24575
  const int which = (id >= 12288);
  const int r = which ? id - 12288 : id;
  const int n = r >> 4, b = r & 15;
  const float* w = (which ? ow : aw) + (size_t)n * Dd;
  const float* ea = eacc + b * Dd;
  float s = 0.f;
#pragma unroll 4
  for (int d = 0; d < Dd; d += 4) {
    const float4 wv = *(const float4*)(w + d);
    const float4 ev = *(const float4*)(ea + d);
    const float4 bv = *(const float4*)(outb + d);
    s += (ev.x * (1.f / 1024.f) + bv.x) * wv.x + (ev.y * (1.f / 1024.f) + bv.y) * wv.y
       + (ev.z * (1.f / 1024.f) + bv.z) * wv.z + (ev.w * (1.f / 1024.f) + bv.w) * wv.w;
  }
  s += which ? ob[n] : ab[n];
  (which ? e2 : e1)[b * Dd + n] = s;
}

__global__ __launch_bounds__(64) void imp_kernel(
    const float* __restrict__ e1, const float* __restrict__ e2,
    const float* __restrict__ wa, const float* __restrict__ ba,
    const float* __restrict__ wo, const float* __restrict__ bo,
    float* __restrict__ outa, float* __restrict__ outo)
{
  const int id = blockIdx.x, lane = threadIdx.x;
  const int b = id >> 2, which = (id >> 1) & 1, c = id & 1;
  const float* e = which ? e2 : e1;
  const float* w = which ? wo : wa;
  const float* bb = which ? bo : ba;
  float s = 0.f;
  for (int d = lane; d < Dd; d += 64) s += e[b * Dd + d] * w[c * Dd + d];
  for (int off = 32; off > 0; off >>= 1) s += __shfl_xor(s, off, 64);
  if (lane == 0) {
    float* o = which ? outo : outa;
    o[b * 2 + c] = s + bb[c];
  }
}

// se1: row0<-e1 then row idx<-e2 ; se2: row idx<-e2 then row0<-e1
__global__ __launch_bounds__(256) void scatter_kernel(
    const float* __restrict__ x, const float* __restrict__ e1,
    const float* __restrict__ e2, const int* __restrict__ idx,
    float* __restrict__ h1, float* __restrict__ h2)
{
  const int row = blockIdx.x;
  const int b = row >> 10, s = row & 1023;
  const int ix = idx[b];
  const size_t base = (size_t)row * Dd;
  for (int i = threadIdx.x; i < Dd; i += 256) {
    const float xv = x[base + i];
    const float v1 = e1[b * Dd + i];
    const float v2 = e2[b * Dd + i];
    h1[base + i] = (s == ix) ? v2 : ((s == 0) ? v1 : xv);
    h2[base + i] = (s == 0) ? v1 : ((s == ix) ? v2 : xv);
  }
}

// h already holds FFN_out + residual (split-K atomics). LayerNorm in place + bf16 shadow.
__global__ __launch_bounds__(64) void ln_kernel(
    float* __restrict__ h, short* __restrict__ hb,
    const float* __restrict__ g, const float* __restrict__ bb)
{
  const int row = blockIdx.x, lane = threadIdx.x;
  const size_t base = (size_t)row * Dd;
  float v[12];
  float s = 0.f, sq = 0.f;
#pragma unroll
  for (int t = 0; t < 12; ++t) {
    const int i = t * 64 + lane;
    const float val = h[base + i];
    v[t] = val;
    s += val;
    sq += val * val;
  }
#pragma unroll
  for (int off = 32; off > 0; off >>= 1) {
    s += __shfl_xor(s, off, 64);
    sq += __shfl_xor(sq, off, 64);
  }
  const float m = s * (1.f / 768.f);
  float var = sq * (1.f / 768.f) - m * m;
  var = fmaxf(var, 0.f);
  const float r = rsqrtf(var + 1e-12f);
#pragma unroll
  for (int t = 0; t < 12; ++t) {
    const int i = t * 64 + lane;
    const float o = (v[t] - m) * r * g[i] + bb[i];
    h[base + i] = o;
    hb[base + i] = f2bf(o);
  }
}

// logits[row,0..2] = h[row,:]@w[c,:] + b[c]; blocks 0..16383 -> asp(h1), rest -> opi(h2)
__global__ __launch_bounds__(64) void logits_kernel(
    const float* __restrict__ h1, const float* __restrict__ h2,
    const float* __restrict__ wa, const float* __restrict__ ba,
    const float* __restrict__ wo, const float* __restrict__ bo,
    float* __restrict__ outa, float* __restrict__ outo)
{
  const int id = blockIdx.x, lane = threadIdx.x;
  const int which = id >> 14;
  const int row = id & 16383;
  const float* h = which ? h2 : h1;
  const float* w = which ? wo : wa;
  const float* bc = which ? bo : ba;
  const size_t base = (size_t)row * Dd;
  float s0 = 0.f, s1 = 0.f, s2 = 0.f;
#pragma unroll
  for (int t = 0; t < 12; ++t) {
    const int i = t * 64 + lane;
    const float hv = h[base + i];
    s0 += hv * w[i];
    s1 += hv * w[Dd + i];
    s2 += hv * w[2 * Dd + i];
  }
#pragma unroll
  for (int off = 32; off > 0; off >>= 1) {
    s0 += __shfl_xor(s0, off, 64);
    s1 += __shfl_xor(s1, off, 64);
    s2 += __shfl_xor(s2, off, 64);
  }
  if (lane == 0) {
    float* o = which ? outo : outa;
    o[(size_t)row * 3 + 0] = s0 + bc[0];
    o[(size_t)row * 3 + 1] = s1 + bc[1];
    o[(size_t)row * 3 + 2] = s2 + bc[2];
  }
}

__global__ __launch_bounds__(256) void copy16(const uint4* __restrict__ s, uint4* __restrict__ d, int n) {
  const int i = blockIdx.x * 256 + threadIdx.x;
  if (i < n) d[i] = s[i];
}

extern "C" void kernel_launch(void* const* d_in, const int* in_sizes, int n_in,
                              void* d_out, int out_size, void* d_ws, size_t ws_size,
                              hipStream_t stream)
{
  (void)in_sizes; (void)n_in; (void)out_size; (void)d_ws; (void)ws_size;  // d_ws UNUSED: size unknown
  const float* x        = (const float*)d_in[0];
  const int*   mask     = (const int*)d_in[1];
  const float* mha_in_w = (const float*)d_in[2];
  const float* mha_in_b = (const float*)d_in[3];
  const float* mha_out_w= (const float*)d_in[4];
  const float* mha_out_b= (const float*)d_in[5];
  const float* asp_w    = (const float*)d_in[6];
  const float* asp_b    = (const float*)d_in[7];
  const float* opi_w    = (const float*)d_in[8];
  const float* opi_b    = (const float*)d_in[9];
  const float* ia_w     = (const float*)d_in[10];
  const float* ia_b     = (const float*)d_in[11];
  const float* io_w     = (const float*)d_in[12];
  const float* io_b     = (const float*)d_in[13];
  const float* cls_a_w  = (const float*)d_in[26];
  const float* cls_a_b  = (const float*)d_in[27];
  const float* cls_o_w  = (const float*)d_in[28];
  const float* cls_o_b  = (const float*)d_in[29];

  // ---- output layout (fp32 elements, return order). ALL scratch lives in dead d_out regions. ----
  float* out   = (float*)d_out;
  float* o_la  = out;                        // logits_asp [16,1024,3]
  float* o_lo  = out + 49152;                // logits_opi; first 64B double as idx[16] until logits
  float* o_x   = out + 98304;                // x copy (written LAST); scratch region (50.33 MB)
  float* o_se1 = o_x + 12582912;             // se1; scratch: qkv bf16 until scatter
  float* o_se2 = o_se1 + 12582912;           // se2
  float* o_ia  = o_se2 + 12582912;           // imp_asp [16,2]
  float* o_io  = o_ia + 32;
  float* o_e1  = o_io + 32;                  // e1 [16,768]
  float* o_e2  = o_e1 + 12288;

  // attention-phase scratch
  short* x_bf   = (short*)o_x;               // [16384,768] bf16 (o_x floats [0 .. 6291456))
  short* ctx_bf = (short*)(o_x + 6291456);   // [16384,768] bf16 (floats [6291456 .. 12582912))
  short* qkv_bf = (short*)o_se1;             // [16384,2304] bf16 = 75.5MB, spans se1+part of se2
  short* win_bf = (short*)(o_se1 + 18874368);// [2304,768] bf16
  short* wout_bf= (short*)(o_se1 + 19759104);// [768,768] bf16 (ends < se2 end)
  float* eacc   = o_x;                       // [16,768] fp32 accum (x_bf head; x_bf dead by then)
  int*   idxp   = (int*)o_lo;                // [16] until logits overwrites

  // FFN-phase scratch (exact fit in o_x = 50,331,648 B; ctx_bf dead by then):
  //   interbuf [4096,3072] bf16 = 25,165,824 B   @ float-offset 0
  //   hb       [4096, 768] bf16 =  6,291,456 B   @ 6291456
  //   wib      [2,3072,768] bf16 = 9,437,184 B   @ 7864320
  //   wob      [2,768,3072] bf16 = 9,437,184 B   @ 10223616  (ends 12582912 ✓)
  short* interbuf = (short*)o_x;
  short* hb       = (short*)(o_x + 6291456);
  short* wib      = (short*)(o_x + 7864320);
  short* wob      = (short*)(o_x + 10223616);

  float* h1 = o_se1;
  float* h2 = o_se2;

  calc_idx<<<Bb, 256, 0, stream>>>(mask, idxp);

  // bf16 conversions: x + MHA weights
  cvt_bf<<<6144, 256, 0, stream>>>(x, x_bf, 1572864);
  cvt_bf<<<864, 256, 0, stream>>>(mha_in_w, win_bf, 221184);
  cvt_bf<<<288, 256, 0, stream>>>(mha_out_w, wout_bf, 73728);

  // QKV gemm (bf16 out) + flash attention (all 16 batches, one launch)
  gemm_bf<EPI_F32, 1><<<dim3(18, 128), 256, 0, stream>>>(
      x_bf, win_bf, mha_in_b, qkv_bf, 2304, 768);
  flash_attn<<<dim3(16, 4, 16), 256, 0, stream>>>(qkv_bf, idxp, ctx_bf);

  // out-proj with fused mean-over-S -> eacc (x_bf region is dead now)
  hipMemsetAsync(eacc, 0, Bb * Dd * sizeof(float), stream);
  gemm_bf<EPI_MEANACC, 0><<<dim3(6, 128), 256, 0, stream>>>(
      ctx_bf, wout_bf, nullptr, eacc, 768, 768);

  e12_kernel<<<96, 256, 0, stream>>>(eacc, mha_out_b, asp_w, asp_b, opi_w, opi_b,
                                     o_e1, o_e2);
  imp_kernel<<<64, 64, 0, stream>>>(o_e1, o_e2, ia_w, ia_b, io_w, io_b, o_ia, o_io);
  scatter_kernel<<<16384, 256, 0, stream>>>(x, o_e1, o_e2, idxp, h1, h2);

  // decoder stacks in place on h1/h2. Super-chunks of 4096 rows:
  //   gelu gemm grid (24,32)=768 blocks; out gemm split-K=4 grid (6,32,4)=768
  //   blocks, partials atomicAdd'd into hc (pre-holds residual); then LN.
  for (int st = 0; st < 2; ++st) {
    float* h = st ? h2 : h1;
    const float* Wi = (const float*)d_in[14 + st * 6];
    const float* bi = (const float*)d_in[15 + st * 6];
    const float* Wo = (const float*)d_in[16 + st * 6];
    const float* bo = (const float*)d_in[17 + st * 6];
    const float* lg = (const float*)d_in[18 + st * 6];
    const float* lb = (const float*)d_in[19 + st * 6];
    cvt_bf<<<2304, 256, 0, stream>>>(Wi, wib, 589824);   // [2,3072,768]
    cvt_bf<<<2304, 256, 0, stream>>>(Wo, wob, 589824);   // [2,768,3072]
    for (int c = 0; c < 4; ++c) {
      float* hc = h + (size_t)c * 4096 * Dd;
      cvt_bf<<<1536, 256, 0, stream>>>(hc, hb, 393216);  // h super-chunk -> bf16
      for (int l = 0; l < 2; ++l) {
        gemm_bf<EPI_GELU, 1><<<dim3(3072 / 128, 4096 / 128), 256, 0, stream>>>(
            hb, wib + (size_t)l * 3072 * 768, bi + l * 3072, interbuf, 3072, 768);
        gemm_bf<EPI_RESAT, 0><<<dim3(768 / 128, 4096 / 128, 4), 256, 0, stream>>>(
            interbuf, wob + (size_t)l * 768 * 3072, bo + l * 768, hc, 768, 3072);
        ln_kernel<<<4096, 64, 0, stream>>>(hc, hb, lg + l * 768, lb + l * 768);
      }
    }
  }

  logits_kernel<<<32768, 64, 0, stream>>>(h1, h2, cls_a_w, cls_a_b, cls_o_w, cls_o_b,
                                          o_la, o_lo);
  // x copy LAST (o_x served as scratch until here)
  copy16<<<12288, 256, 0, stream>>>((const uint4*)x, (uint4*)o_x, 3145728);
}

// Round 5
// 2091.893 us; speedup vs baseline: 5.9082x; 1.0775x over previous
//
#include <hip/hip_runtime.h>
#include <hip/hip_bf16.h>
#include <stdint.h>

// Problem dims (fixed): B=16 S=1024 D=768 NH=4 hd=192 DFF=3072 NL=2 C=3
#define Bb 16
#define Ss 1024
#define Dd 768
#define HDd 192

typedef __attribute__((ext_vector_type(8))) short short8;   // 8 bf16 (4 VGPRs)
typedef __attribute__((ext_vector_type(4))) short short4a;  // 4 bf16 (2 VGPRs)
typedef __attribute__((ext_vector_type(4))) float f32x4;

__device__ __forceinline__ short f2bf(float f) {
  union { __hip_bfloat16 h; short s; } u;
  u.h = __float2bfloat16(f);
  return u.s;
}
__device__ __forceinline__ short8 cvt8(float4 lo, float4 hi) {
  short8 r;
  r[0] = f2bf(lo.x); r[1] = f2bf(lo.y); r[2] = f2bf(lo.z); r[3] = f2bf(lo.w);
  r[4] = f2bf(hi.x); r[5] = f2bf(hi.y); r[6] = f2bf(hi.z); r[7] = f2bf(hi.w);
  return r;
}
// async global->LDS 16B (m97 staging). LDS dest is wave-uniform base + lane*16:
// per-lane dest pointers must be lane-contiguous within each wave.
__device__ __forceinline__ void gload_lds16(const void* g, void* l) {
  __builtin_amdgcn_global_load_lds(
      (const __attribute__((address_space(1))) void*)g,
      (__attribute__((address_space(3))) void*)l, 16, 0, 0);
}

enum { EPI_F32 = 0, EPI_GELU = 1, EPI_MEANACC = 2, EPI_RESAT = 3 };

// C[m,n] = sum_k A[m,k]*Bw[n,k] (+bias[n], +epilogue). bf16 operands in global.
// m97 structure, BK=64: global_load_lds width-16 staging, 128x128 tile,
// 32 MFMA per barrier pair. LDS rows are 8x16B units XOR-swizzled by row&7
// (rule 21: linear LDS dest + inverse-swizzled global SOURCE + swizzled read).
// EPI_RESAT: split-K over blockIdx.z (4 quarters); partial sums atomicAdd into
// out (which pre-holds the residual); bias contributed by the kz==0 block only.
// OBF=1 -> store bf16 (consumer is another gemm), else fp32.
template <int EPI, int OBF>
__global__ __launch_bounds__(256) void gemm_bf(
    const short* __restrict__ A, const short* __restrict__ Bw,
    const float* __restrict__ bias, void* __restrict__ outp,
    const int N, const int K)
{
  constexpr int TM = 128, TN = 128, BK = 64;
  __shared__ __align__(16) short As[TM * BK];   // 16 KB
  __shared__ __align__(16) short Bs[TN * BK];   // 16 KB

  const int tid = threadIdx.x;
  const int wave = tid >> 6, lane = tid & 63;
  const int l16 = lane & 15, quad = lane >> 4;
  const int wm = wave >> 1, wn = wave & 1;
  const size_t m0 = (size_t)blockIdx.y * TM;
  const size_t n0 = (size_t)blockIdx.x * TN;
  const int kz = blockIdx.z;                     // split-K index (EPI_RESAT)
  const int kbeg = (EPI == EPI_RESAT) ? kz * (K >> 2) : 0;
  const int kend = (EPI == EPI_RESAT) ? kbeg + (K >> 2) : K;

  // staging: 1024 16B-units per matrix; thread stages units tid+256*i (i<4).
  // unit c -> (row=c>>3, physical u=c&7) holding global logical unit u^(row&7).
  // row_i = srow+32i keeps row&7 and u constant across i.
  const int srow = tid >> 3;
  const int sunit = (tid & 7) ^ (srow & 7);
  const short* Ag = A + (m0 + srow) * K + sunit * 8;
  const short* Bg = Bw + (n0 + srow) * K + sunit * 8;
  short* Asd = &As[tid * 8];
  short* Bsd = &Bs[tid * 8];

  f32x4 acc[4][4];
#pragma unroll
  for (int i = 0; i < 4; ++i)
#pragma unroll
    for (int j = 0; j < 4; ++j) acc[i][j] = (f32x4){0.f, 0.f, 0.f, 0.f};

#pragma unroll 1
  for (int k0 = kbeg; k0 < kend; k0 += BK) {
    __syncthreads();                 // WAR: prev iter's LDS reads done
#pragma unroll
    for (int i = 0; i < 4; ++i) {
      gload_lds16(Ag + (size_t)(32 * i) * K + k0, Asd + 2048 * i);
      gload_lds16(Bg + (size_t)(32 * i) * K + k0, Bsd + 2048 * i);
    }
    __syncthreads();                 // RAW: vmcnt drained before barrier

#pragma unroll
    for (int kh = 0; kh < 2; ++kh) {
      short8 af[4], bfr[4];
#pragma unroll
      for (int i = 0; i < 4; ++i) {
        const int arow = wm * 64 + i * 16 + l16;   // arow&7 == l16&7
        const int pu = ((kh * 4 + quad) ^ (l16 & 7)) * 8;
        af[i]  = *(const short8*)&As[arow * BK + pu];
        bfr[i] = *(const short8*)&Bs[(wn * 64 + i * 16 + l16) * BK + pu];
      }
#pragma unroll
      for (int mt = 0; mt < 4; ++mt)
#pragma unroll
        for (int nt = 0; nt < 4; ++nt)
          acc[mt][nt] = __builtin_amdgcn_mfma_f32_16x16x32_bf16(af[mt], bfr[nt], acc[mt][nt], 0, 0, 0);
    }
  }

  if constexpr (EPI == EPI_MEANACC) {
    // fused mean-over-S: column sums -> atomicAdd into [B,D] fp32 accumulator
    float* eacc = (float*)outp;
    const int b = (int)(m0 >> 10);   // 1024 rows per batch; 128-row tiles never straddle
#pragma unroll
    for (int nt = 0; nt < 4; ++nt) {
      float cs = 0.f;
#pragma unroll
      for (int mt = 0; mt < 4; ++mt)
#pragma unroll
        for (int r = 0; r < 4; ++r) cs += acc[mt][nt][r];
      cs += __shfl_xor(cs, 16, 64);
      cs += __shfl_xor(cs, 32, 64);
      if (quad == 0) {
        const int col = (int)n0 + wn * 64 + nt * 16 + l16;
        atomicAdd(&eacc[b * Dd + col], cs);
      }
    }
  } else if constexpr (EPI == EPI_RESAT) {
    // split-K partial: atomicAdd into out (pre-holds residual h)
    float* outf = (float*)outp;
#pragma unroll
    for (int nt = 0; nt < 4; ++nt) {
      const size_t col = n0 + wn * 64 + nt * 16 + l16;
      const float bv = (kz == 0) ? bias[col] : 0.f;
#pragma unroll
      for (int mt = 0; mt < 4; ++mt) {
#pragma unroll
        for (int r = 0; r < 4; ++r) {
          const size_t row = m0 + wm * 64 + mt * 16 + quad * 4 + r;
          atomicAdd(&outf[row * N + col], acc[mt][nt][r] + bv);
        }
      }
    }
  } else {
#pragma unroll
    for (int nt = 0; nt < 4; ++nt) {
      const size_t col = n0 + wn * 64 + nt * 16 + l16;
      const float bv = bias[col];
#pragma unroll
      for (int mt = 0; mt < 4; ++mt) {
#pragma unroll
        for (int r = 0; r < 4; ++r) {
          const size_t row = m0 + wm * 64 + mt * 16 + quad * 4 + r;
          float v = acc[mt][nt][r] + bv;
          if constexpr (EPI == EPI_GELU)
            v = 0.5f * v * (1.f + erff(v * 0.70710678118654752f));
          if constexpr (OBF)
            ((short*)outp)[row * N + col] = f2bf(v);
          else
            ((float*)outp)[row * N + col] = v;
        }
      }
    }
  }
}

// ---- MFMA flash attention on bf16 qkv ---------------------------------------
// grid dim3(16,4,16): x = q-tile, y = head, z = batch (qt-fast: spreads each
// (b,h)'s q-tiles across XCDs. The XCD-pinned variant cut FETCH 163->51MB but
// ran 8% SLOWER (R3): not HBM-bound, and pinning serialized K/V behind one L2).
// 4 waves/block, each wave owns 16 q rows. Swapped QK^T; K tile staged via
// global_load_lds with source-side swizzle; V^T via register transpose.
// R5: P-buffer overlaid on Ks head (live ranges disjoint, separated by an extra
// barrier after QK^T) -> LDS 56->48KB -> 3 blocks/CU instead of 2.
__global__ __launch_bounds__(256, 3) void flash_attn(
    const short* __restrict__ qkv, const int* __restrict__ idxp,
    short* __restrict__ ctx)
{
  __shared__ __align__(16) short Ks[64 * 192];    // 24.0 KB (head 8KB = P after QK^T)
  __shared__ __align__(16) short Vt[192 * 64];    // 24.0 KB

  const int tid = threadIdx.x, wave = tid >> 6, lane = tid & 63;
  const int l16 = lane & 15, quad = lane >> 4;
  const int qt = blockIdx.x, h = blockIdx.y, b = blockIdx.z;
  const int L = idxp[b] + 1;                      // number of valid keys
  const short* base = qkv + (size_t)b * Ss * (3 * Dd);
  const short* Kb = base + Dd + h * HDd;
  const short* Vb = base + 2 * Dd + h * HDd;
  short* Ps = &Ks[wave * 1024];                   // per-wave 16x64 P (2KB), overlaid

  // Q fragments (MFMA B-operand): direct bf16 loads
  short8 qf[6];
  {
    const short* qp = base + (size_t)(qt * 64 + wave * 16 + l16) * (3 * Dd) + h * HDd;
#pragma unroll
    for (int c = 0; c < 6; ++c) qf[c] = *(const short8*)(qp + c * 32 + quad * 8);
  }

  f32x4 acc[12];                                  // O accum: 16 q x 192 d per wave
#pragma unroll
  for (int i = 0; i < 12; ++i) acc[i] = (f32x4){0.f, 0.f, 0.f, 0.f};
  float m = -3.0e38f, l = 0.f;
  const float scale = 0.07216878364870322f;       // 1/sqrt(192)

#pragma unroll 1
  for (int kt = 0; kt < 16; ++kt) {
    const int k0 = kt * 64;
    if (k0 >= L) break;                           // prefix mask: rest is masked (uniform)
    __syncthreads();                              // WAR on Ks(P)/Vt

    // stage K tile [64 k][192 hd] via gload_lds; physical 16B-unit (kk,u) holds
    // global unit u^(kk&7) so the swizzled read below lands on logical data
#pragma unroll
    for (int i = 0; i < 6; ++i) {
      const int c = tid + 256 * i;
      const int kk = c / 24, u = c % 24;
      gload_lds16(Kb + (size_t)(k0 + kk) * (3 * Dd) + (u ^ (kk & 7)) * 8, &Ks[c * 8]);
    }
    // stage V^T tile [192 d][64 k]: pack (k,k+1) bf16 pairs, swizzled
#pragma unroll
    for (int i = 0; i < 6; ++i) {
      const int c = tid + 256 * i;
      const int kp2 = (c & 31) * 2, dc = (c >> 5) * 4;
      const short* vp = Vb + (size_t)(k0 + kp2) * (3 * Dd) + dc;
      const short4a va  = *(const short4a*)vp;
      const short4a vb4 = *(const short4a*)(vp + 3 * Dd);
#pragma unroll
      for (int j = 0; j < 4; ++j) {
        const int d = dc + j;
        const unsigned int pr = (unsigned int)(unsigned short)va[j] |
                                ((unsigned int)(unsigned short)vb4[j] << 16);
        *(unsigned int*)&Vt[(d * 64 + kp2) ^ ((d & 7) << 3)] = pr;
      }
    }
    __syncthreads();                              // RAW (vmcnt+lgkm drained)

    // S^T tile [64 k][16 q] = K·Q^T
    f32x4 accS[4];
#pragma unroll
    for (int mt = 0; mt < 4; ++mt) accS[mt] = (f32x4){0.f, 0.f, 0.f, 0.f};
#pragma unroll
    for (int c = 0; c < 6; ++c) {
      short8 kf[4];
#pragma unroll
      for (int mt = 0; mt < 4; ++mt) {
        const int row = mt * 16 + l16;
        kf[mt] = *(const short8*)&Ks[(row * 192 + c * 32 + quad * 8) ^ ((l16 & 7) << 3)];
      }
#pragma unroll
      for (int mt = 0; mt < 4; ++mt)
        accS[mt] = __builtin_amdgcn_mfma_f32_16x16x32_bf16(kf[mt], qf[c], accS[mt], 0, 0, 0);
    }

    // lane holds k = k0 + mt*16 + quad*4 + r for q = l16 : scale + padding mask
    float tm = -3.0e38f;
#pragma unroll
    for (int mt = 0; mt < 4; ++mt) {
      const int kg = k0 + mt * 16 + quad * 4;
#pragma unroll
      for (int r = 0; r < 4; ++r) {
        const float sv = (kg + r < L) ? accS[mt][r] * scale : -1.0e30f;
        accS[mt][r] = sv;
        tm = fmaxf(tm, sv);
      }
    }
    tm = fmaxf(tm, __shfl_xor(tm, 16));
    tm = fmaxf(tm, __shfl_xor(tm, 32));
    const float mn = fmaxf(m, tm);
    const bool stay = (mn == m);
    const float sf = __expf(m - mn);
    m = mn;
    l *= sf;

    __syncthreads();   // ALL waves' QK^T Ks-reads done before P overwrites Ks head

    float rs = 0.f;
#pragma unroll
    for (int mt = 0; mt < 4; ++mt) {
      short4a pw;
#pragma unroll
      for (int r = 0; r < 4; ++r) {
        const float p = __expf(accS[mt][r] - mn);
        rs += p;
        pw[r] = f2bf(p);
      }
      *(short4a*)&Ps[(l16 * 64 + mt * 16 + quad * 4) ^ ((l16 & 7) << 3)] = pw;
    }
    rs += __shfl_xor(rs, 16);
    rs += __shfl_xor(rs, 32);
    l += rs;

    if (!__all(stay)) {                           // defer-rescale (T13)
      f32x4 sv_;
#pragma unroll
      for (int r = 0; r < 4; ++r) sv_[r] = __shfl(sf, quad * 4 + r);
#pragma unroll
      for (int nt = 0; nt < 12; ++nt)
#pragma unroll
        for (int r = 0; r < 4; ++r) acc[nt][r] *= sv_[r];
    }

    // O += P·V  (Ps reads are same-wave after same-wave writes: lgkm-ordered)
#pragma unroll
    for (int ks = 0; ks < 2; ++ks) {
      const short8 pa =
          *(const short8*)&Ps[(l16 * 64 + ks * 32 + quad * 8) ^ ((l16 & 7) << 3)];
#pragma unroll
      for (int nt = 0; nt < 12; ++nt) {
        const int d = nt * 16 + l16;
        const short8 vb =
            *(const short8*)&Vt[(d * 64 + ks * 32 + quad * 8) ^ ((d & 7) << 3)];
        acc[nt] = __builtin_amdgcn_mfma_f32_16x16x32_bf16(pa, vb, acc[nt], 0, 0, 0);
      }
    }
  }

  // epilogue: normalize and write ctx[b, q, h*192 + d] as bf16
  const float inv = 1.f / l;
  f32x4 iv;
#pragma unroll
  for (int r = 0; r < 4; ++r) iv[r] = __shfl(inv, quad * 4 + r);
  const int qrow = qt * 64 + wave * 16;
#pragma unroll
  for (int r = 0; r < 4; ++r) {
    short* cp = ctx + ((size_t)b * Ss + qrow + quad * 4 + r) * Dd + h * HDd + l16;
#pragma unroll
    for (int nt = 0; nt < 12; ++nt) cp[nt * 16] = f2bf(acc[nt][r] * iv[r]);
  }
}

__global__ __launch_bounds__(256) void calc_idx(const int* __restrict__ mask, int* __restrict__ idx) {
  __shared__ int sm[256];
  const int b = blockIdx.x, tid = threadIdx.x;
  int s = 0;
  for (int i = tid; i < Ss; i += 256) s += mask[b * Ss + i];
  sm[tid] = s;
  __syncthreads();
  for (int o = 128; o > 0; o >>= 1) {
    if (tid < o) sm[tid] += sm[tid + o];
    __syncthreads();
  }
  if (tid == 0) idx[b] = sm[0] - 1;
}

// fp32 -> bf16, 8 elems/thread
__global__ __launch_bounds__(256) void cvt_bf(const float* __restrict__ s,
                                              short* __restrict__ d, int n8) {
  const int i = blockIdx.x * 256 + threadIdx.x;
  if (i < n8)
    *(short8*)(d + (size_t)i * 8) = cvt8(((const float4*)s)[i * 2],
                                         ((const float4*)s)[i * 2 + 1]);
}

// e1/e2: one thread per (which,n,b). 16-lane groups share a w-row (broadcast loads).
// emb[b][d] = eacc[b][d]/1024 + outb[d] recomputed in-flight (trivial FLOPs).
__global__ __launch_bounds__(256) void e12_kernel(
    const float* __restrict__ eacc, const float* __restrict__ outb,
    const float* __restrict__ aw, const float* __restrict__ ab,
    const float* __restrict__ ow, const float* __restrict__ ob,
    float* __restrict__ e1, float* __restrict__ e2)
{
  const int id = blockIdx.x * 256 + threadIdx.x;  // 0..24575
  const int which = (id >= 12288);
  const int r = which ? id - 12288 : id;
  const int n = r >> 4, b = r & 15;
  const float* w = (which ? ow : aw) + (size_t)n * Dd;
  const float* ea = eacc + b * Dd;
  float s = 0.f;
#pragma unroll 4
  for (int d = 0; d < Dd; d += 4) {
    const float4 wv = *(const float4*)(w + d);
    const float4 ev = *(const float4*)(ea + d);
    const float4 bv = *(const float4*)(outb + d);
    s += (ev.x * (1.f / 1024.f) + bv.x) * wv.x + (ev.y * (1.f / 1024.f) + bv.y) * wv.y
       + (ev.z * (1.f / 1024.f) + bv.z) * wv.z + (ev.w * (1.f / 1024.f) + bv.w) * wv.w;
  }
  s += which ? ob[n] : ab[n];
  (which ? e2 : e1)[b * Dd + n] = s;
}

__global__ __launch_bounds__(64) void imp_kernel(
    const float* __restrict__ e1, const float* __restrict__ e2,
    const float* __restrict__ wa, const float* __restrict__ ba,
    const float* __restrict__ wo, const float* __restrict__ bo,
    float* __restrict__ outa, float* __restrict__ outo)
{
  const int id = blockIdx.x, lane = threadIdx.x;
  const int b = id >> 2, which = (id >> 1) & 1, c = id & 1;
  const float* e = which ? e2 : e1;
  const float* w = which ? wo : wa;
  const float* bb = which ? bo : ba;
  float s = 0.f;
  for (int d = lane; d < Dd; d += 64) s += e[b * Dd + d] * w[c * Dd + d];
  for (int off = 32; off > 0; off >>= 1) s += __shfl_xor(s, off, 64);
  if (lane == 0) {
    float* o = which ? outo : outa;
    o[b * 2 + c] = s + bb[c];
  }
}

// se1: row0<-e1 then row idx<-e2 ; se2: row idx<-e2 then row0<-e1.
// xc != nullptr: also emit the x copy (big-ws path; o_x is dead scratch by now).
__global__ __launch_bounds__(256) void scatter_kernel(
    const float* __restrict__ x, const float* __restrict__ e1,
    const float* __restrict__ e2, const int* __restrict__ idx,
    float* __restrict__ h1, float* __restrict__ h2, float* __restrict__ xc)
{
  const int row = blockIdx.x;
  const int b = row >> 10, s = row & 1023;
  const int ix = idx[b];
  const size_t base = (size_t)row * Dd;
  for (int i = threadIdx.x; i < Dd; i += 256) {
    const float xv = x[base + i];
    const float v1 = e1[b * Dd + i];
    const float v2 = e2[b * Dd + i];
    h1[base + i] = (s == ix) ? v2 : ((s == 0) ? v1 : xv);
    h2[base + i] = (s == 0) ? v1 : ((s == ix) ? v2 : xv);
    if (xc) xc[base + i] = xv;
  }
}

// h already holds FFN_out + residual (split-K atomics). LayerNorm in place + bf16 shadow.
__global__ __launch_bounds__(64) void ln_kernel(
    float* __restrict__ h, short* __restrict__ hb,
    const float* __restrict__ g, const float* __restrict__ bb)
{
  const int row = blockIdx.x, lane = threadIdx.x;
  const size_t base = (size_t)row * Dd;
  float v[12];
  float s = 0.f, sq = 0.f;
#pragma unroll
  for (int t = 0; t < 12; ++t) {
    const int i = t * 64 + lane;
    const float val = h[base + i];
    v[t] = val;
    s += val;
    sq += val * val;
  }
#pragma unroll
  for (int off = 32; off > 0; off >>= 1) {
    s += __shfl_xor(s, off, 64);
    sq += __shfl_xor(sq, off, 64);
  }
  const float m = s * (1.f / 768.f);
  float var = sq * (1.f / 768.f) - m * m;
  var = fmaxf(var, 0.f);
  const float r = rsqrtf(var + 1e-12f);
#pragma unroll
  for (int t = 0; t < 12; ++t) {
    const int i = t * 64 + lane;
    const float o = (v[t] - m) * r * g[i] + bb[i];
    h[base + i] = o;
    hb[base + i] = f2bf(o);
  }
}

// logits[row,0..2] = h[row,:]@w[c,:] + b[c]; blocks 0..16383 -> asp(h1), rest -> opi(h2)
__global__ __launch_bounds__(64) void logits_kernel(
    const float* __restrict__ h1, const float* __restrict__ h2,
    const float* __restrict__ wa, const float* __restrict__ ba,
    const float* __restrict__ wo, const float* __restrict__ bo,
    float* __restrict__ outa, float* __restrict__ outo)
{
  const int id = blockIdx.x, lane = threadIdx.x;
  const int which = id >> 14;
  const int row = id & 16383;
  const float* h = which ? h2 : h1;
  const float* w = which ? wo : wa;
  const float* bc = which ? bo : ba;
  const size_t base = (size_t)row * Dd;
  float s0 = 0.f, s1 = 0.f, s2 = 0.f;
#pragma unroll
  for (int t = 0; t < 12; ++t) {
    const int i = t * 64 + lane;
    const float hv = h[base + i];
    s0 += hv * w[i];
    s1 += hv * w[Dd + i];
    s2 += hv * w[2 * Dd + i];
  }
#pragma unroll
  for (int off = 32; off > 0; off >>= 1) {
    s0 += __shfl_xor(s0, off, 64);
    s1 += __shfl_xor(s1, off, 64);
    s2 += __shfl_xor(s2, off, 64);
  }
  if (lane == 0) {
    float* o = which ? outo : outa;
    o[(size_t)row * 3 + 0] = s0 + bc[0];
    o[(size_t)row * 3 + 1] = s1 + bc[1];
    o[(size_t)row * 3 + 2] = s2 + bc[2];
  }
}

__global__ __launch_bounds__(256) void copy16(const uint4* __restrict__ s, uint4* __restrict__ d, int n) {
  const int i = blockIdx.x * 256 + threadIdx.x;
  if (i < n) d[i] = s[i];
}

extern "C" void kernel_launch(void* const* d_in, const int* in_sizes, int n_in,
                              void* d_out, int out_size, void* d_ws, size_t ws_size,
                              hipStream_t stream)
{
  (void)in_sizes; (void)n_in; (void)out_size;
  const float* x        = (const float*)d_in[0];
  const int*   mask     = (const int*)d_in[1];
  const float* mha_in_w = (const float*)d_in[2];
  const float* mha_in_b = (const float*)d_in[3];
  const float* mha_out_w= (const float*)d_in[4];
  const float* mha_out_b= (const float*)d_in[5];
  const float* asp_w    = (const float*)d_in[6];
  const float* asp_b    = (const float*)d_in[7];
  const float* opi_w    = (const float*)d_in[8];
  const float* opi_b    = (const float*)d_in[9];
  const float* ia_w     = (const float*)d_in[10];
  const float* ia_b     = (const float*)d_in[11];
  const float* io_w     = (const float*)d_in[12];
  const float* io_b     = (const float*)d_in[13];
  const float* cls_a_w  = (const float*)d_in[26];
  const float* cls_a_b  = (const float*)d_in[27];
  const float* cls_o_w  = (const float*)d_in[28];
  const float* cls_o_b  = (const float*)d_in[29];

  // ---- output layout (fp32 elements, return order). ALL scratch lives in dead d_out regions. ----
  float* out   = (float*)d_out;
  float* o_la  = out;                        // logits_asp [16,1024,3]
  float* o_lo  = out + 49152;                // logits_opi; first 64B double as idx[16] until logits
  float* o_x   = out + 98304;                // x copy; scratch region (50.33 MB) until written
  float* o_se1 = o_x + 12582912;             // se1; scratch: qkv bf16 until scatter
  float* o_se2 = o_se1 + 12582912;           // se2
  float* o_ia  = o_se2 + 12582912;           // imp_asp [16,2]
  float* o_io  = o_ia + 32;
  float* o_e1  = o_io + 32;                  // e1 [16,768]
  float* o_e2  = o_e1 + 12288;

  // attention-phase scratch
  short* x_bf   = (short*)o_x;               // [16384,768] bf16 (o_x floats [0 .. 6291456))
  short* ctx_bf = (short*)(o_x + 6291456);   // [16384,768] bf16 (floats [6291456 .. 12582912))
  short* qkv_bf = (short*)o_se1;             // [16384,2304] bf16 = 75.5MB, spans se1+part of se2
  short* win_bf = (short*)(o_se1 + 18874368);// [2304,768] bf16
  short* wout_bf= (short*)(o_se1 + 19759104);// [768,768] bf16 (ends < se2 end)
  float* eacc   = o_x;                       // [16,768] fp32 accum (x_bf head; x_bf dead by then)
  int*   idxp   = (int*)o_lo;                // [16] until logits overwrites

  // FFN-phase scratch. Two tiers:
  //  big (ws_size >= 146MB): everything in d_ws, ONE 16384-row chunk per layer,
  //    o_x dead after e12 -> x copy fused into scatter (skip copy16).
  //    ws shorts: interbuf [16384,3072] @0 (50,331,648 sh), hb [16384,768]
  //    @50331648, wib [2,3072,768] @62914560, wob @67633152 (end 144.7MB).
  //  small: previous exact-fit layout in o_x, 4 chunks of 4096 rows.
  const bool big = (ws_size >= (size_t)146 * 1024 * 1024);
  short* ws_s = (short*)d_ws;
  short* interbuf = big ? ws_s            : (short*)o_x;
  short* hb       = big ? ws_s + 50331648 : (short*)(o_x + 6291456);
  short* wib      = big ? ws_s + 62914560 : (short*)(o_x + 7864320);
  short* wob      = big ? ws_s + 67633152 : (short*)(o_x + 10223616);
  const int Mc = big ? 16384 : 4096;
  const int nc = big ? 1 : 4;

  float* h1 = o_se1;
  float* h2 = o_se2;

  calc_idx<<<Bb, 256, 0, stream>>>(mask, idxp);

  // bf16 conversions: x + MHA weights
  cvt_bf<<<6144, 256, 0, stream>>>(x, x_bf, 1572864);
  cvt_bf<<<864, 256, 0, stream>>>(mha_in_w, win_bf, 221184);
  cvt_bf<<<288, 256, 0, stream>>>(mha_out_w, wout_bf, 73728);

  // QKV gemm (bf16 out) + flash attention (all 16 batches, one launch)
  gemm_bf<EPI_F32, 1><<<dim3(18, 128), 256, 0, stream>>>(
      x_bf, win_bf, mha_in_b, qkv_bf, 2304, 768);
  flash_attn<<<dim3(16, 4, 16), 256, 0, stream>>>(qkv_bf, idxp, ctx_bf);

  // out-proj with fused mean-over-S -> eacc (x_bf region is dead now)
  hipMemsetAsync(eacc, 0, Bb * Dd * sizeof(float), stream);
  gemm_bf<EPI_MEANACC, 0><<<dim3(6, 128), 256, 0, stream>>>(
      ctx_bf, wout_bf, nullptr, eacc, 768, 768);

  e12_kernel<<<96, 256, 0, stream>>>(eacc, mha_out_b, asp_w, asp_b, opi_w, opi_b,
                                     o_e1, o_e2);
  imp_kernel<<<64, 64, 0, stream>>>(o_e1, o_e2, ia_w, ia_b, io_w, io_b, o_ia, o_io);
  scatter_kernel<<<16384, 256, 0, stream>>>(x, o_e1, o_e2, idxp, h1, h2,
                                            big ? o_x : nullptr);

  // decoder stacks in place on h1/h2, nc chunks of Mc rows:
  //   gelu gemm grid (24,Mc/128); out gemm split-K=4 grid (6,Mc/128,4),
  //   partials atomicAdd'd into hc (pre-holds residual); then LN + bf16 shadow.
  for (int st = 0; st < 2; ++st) {
    float* h = st ? h2 : h1;
    const float* Wi = (const float*)d_in[14 + st * 6];
    const float* bi = (const float*)d_in[15 + st * 6];
    const float* Wo = (const float*)d_in[16 + st * 6];
    const float* bo = (const float*)d_in[17 + st * 6];
    const float* lg = (const float*)d_in[18 + st * 6];
    const float* lb = (const float*)d_in[19 + st * 6];
    cvt_bf<<<2304, 256, 0, stream>>>(Wi, wib, 589824);   // [2,3072,768]
    cvt_bf<<<2304, 256, 0, stream>>>(Wo, wob, 589824);   // [2,768,3072]
    for (int c = 0; c < nc; ++c) {
      float* hc = h + (size_t)c * Mc * Dd;
      cvt_bf<<<Mc * 96 / 256, 256, 0, stream>>>(hc, hb, Mc * 96);  // h chunk -> bf16
      for (int l = 0; l < 2; ++l) {
        gemm_bf<EPI_GELU, 1><<<dim3(3072 / 128, Mc / 128), 256, 0, stream>>>(
            hb, wib + (size_t)l * 3072 * 768, bi + l * 3072, interbuf, 3072, 768);
        gemm_bf<EPI_RESAT, 0><<<dim3(768 / 128, Mc / 128, 4), 256, 0, stream>>>(
            interbuf, wob + (size_t)l * 768 * 3072, bo + l * 768, hc, 768, 3072);
        ln_kernel<<<Mc, 64, 0, stream>>>(hc, hb, lg + l * 768, lb + l * 768);
      }
    }
  }

  logits_kernel<<<32768, 64, 0, stream>>>(h1, h2, cls_a_w, cls_a_b, cls_o_w, cls_o_b,
                                          o_la, o_lo);
  // x copy LAST only in the small-ws path (o_x was scratch until here)
  if (!big)
    copy16<<<12288, 256, 0, stream>>>((const uint4*)x, (uint4*)o_x, 3145728);
}